// Round 1
// 12252.153 us; speedup vs baseline: 1.2142x; 1.2142x over previous
//
#include <hip/hip_runtime.h>
#include <hip/hip_bf16.h>

#define NB  4096
#define NT  128
#define ND  64
#define NV  65
#define NL  3
#define NH  8
#define NDF 256
#define NBT (NB*NT)

// fp32 param offsets inside d_ws (element counts)
#define OFF_TOK   0
#define OFF_POS   4160
#define OFF_LN1G  12352
#define OFF_LN1B  12544
#define OFF_WQ    12736
#define OFF_WK    25024
#define OFF_WV    37312
#define OFF_WO    49600
#define OFF_BO    61888
#define OFF_LN2G  62080
#define OFF_LN2B  62272
#define OFF_W1    62464
#define OFF_B1    111616
#define OFF_W2    112384
#define OFF_B2    161536
#define OFF_LNFG  161728
#define OFF_LNFB  161792
#define OFF_LMW   161856
#define OFF_LMB   166016
#define CVT_TOTAL 166081
#define OFF_LOSS  166144   // fp32 loss accumulator slot
#define OFF_FLAG  166145   // flags: bit0 = floats are fp32; bit2 = ints proven int32

struct CvtArgs { const void* p[19]; };

__global__ void diag_fill(float* __restrict__ out, int n, float val) {
    int i = blockIdx.x * 256 + threadIdx.x;
    if (i < n) out[i] = val;
}

// Float dtype sniff (r1-vs-r2 A/B established fp32; keep it robust).
__global__ void detect_float(const unsigned short* __restrict__ tok,
                             int* __restrict__ flags) {
    int bad = 0;
    for (int i = threadIdx.x; i < 4096; i += 256) {
        float v = __uint_as_float(((unsigned int)tok[i]) << 16);
        if (!(fabsf(v) < 1000.f)) bad = 1;
    }
    if (bad) atomicOr(flags, 1);
}

// Int width sniff (r2-vs-r3 A/B established int32; keep robust).
__global__ void detect_int(const int* __restrict__ idx32,
                           int* __restrict__ flags) {
    int proven = 0;
    #pragma unroll
    for (int j = 0; j < 8; j++) {
        int slot = 2 * (threadIdx.x * 8 + j) + 1;
        if (idx32[slot] != 0) proven = 1;
    }
    if (proven) atomicOr(flags, 4);
}

// param conversion (bf16 or fp32 -> fp32) into workspace
__global__ void cvt_params(CvtArgs a, float* __restrict__ W,
                           const int* __restrict__ flags) {
    int tid = blockIdx.x * 256 + threadIdx.x;
    if (tid >= CVT_TOTAL) return;
    const int offs[20] = {0,4160,12352,12544,12736,25024,37312,49600,61888,
                          62080,62272,62464,111616,112384,161536,161728,
                          161792,161856,166016,166081};
    int s = 0;
    #pragma unroll
    for (int k = 1; k < 19; k++) s += (tid >= offs[k]);
    int local = tid - offs[s];
    if (*flags & 1) {
        W[tid] = ((const float*)a.p[s])[local];
    } else {
        unsigned int v = ((const unsigned short*)a.p[s])[local];
        W[tid] = __uint_as_float(v << 16);
    }
}

__device__ __forceinline__ unsigned short f2bf(float x) {
    unsigned int u = __float_as_uint(x);
    u = (u + 0x7fffu + ((u >> 16) & 1u)) >> 16;   // RNE
    return (unsigned short)u;
}

__device__ __forceinline__ void unpack8(uint4 u, float* f) {
    f[0] = __uint_as_float(u.x << 16); f[1] = __uint_as_float(u.x & 0xffff0000u);
    f[2] = __uint_as_float(u.y << 16); f[3] = __uint_as_float(u.y & 0xffff0000u);
    f[4] = __uint_as_float(u.z << 16); f[5] = __uint_as_float(u.z & 0xffff0000u);
    f[6] = __uint_as_float(u.w << 16); f[7] = __uint_as_float(u.w & 0xffff0000u);
}

// LayerNorm over D=64, 8 threads per row (1024 threads cover 128 rows)
__device__ __forceinline__ void ln_helper(const float (*src)[68], float (*dst)[68],
                                          const float* __restrict__ g,
                                          const float* __restrict__ bb, int tid) {
    int r = tid >> 3, q = tid & 7;
    int c0 = q * 8;
    float s = 0.f, s2 = 0.f;
    #pragma unroll
    for (int c = 0; c < 8; c++) { float v = src[r][c0 + c]; s += v; s2 += v * v; }
    s += __shfl_xor(s, 1);  s2 += __shfl_xor(s2, 1);
    s += __shfl_xor(s, 2);  s2 += __shfl_xor(s2, 2);
    s += __shfl_xor(s, 4);  s2 += __shfl_xor(s2, 4);
    float mu   = s  * (1.f / 64.f);
    float var  = s2 * (1.f / 64.f) - mu * mu;
    float rstd = rsqrtf(var + 1e-5f);
    #pragma unroll
    for (int c = 0; c < 8; c++) {
        int cc = c0 + c;
        dst[r][cc] = (src[r][cc] - mu) * rstd * g[cc] + bb[cc];
    }
}

// 16 FMAs of one activation row segment (LDS broadcast) against cached weights
__device__ __forceinline__ void fma16(const float* xr, const float* wr, float& a) {
    float4 x0 = *(const float4*)(xr);
    float4 x1 = *(const float4*)(xr + 4);
    float4 x2 = *(const float4*)(xr + 8);
    float4 x3 = *(const float4*)(xr + 12);
    a = fmaf(x0.x, wr[0],  a); a = fmaf(x0.y, wr[1],  a);
    a = fmaf(x0.z, wr[2],  a); a = fmaf(x0.w, wr[3],  a);
    a = fmaf(x1.x, wr[4],  a); a = fmaf(x1.y, wr[5],  a);
    a = fmaf(x1.z, wr[6],  a); a = fmaf(x1.w, wr[7],  a);
    a = fmaf(x2.x, wr[8],  a); a = fmaf(x2.y, wr[9],  a);
    a = fmaf(x2.z, wr[10], a); a = fmaf(x2.w, wr[11], a);
    a = fmaf(x3.x, wr[12], a); a = fmaf(x3.y, wr[13], a);
    a = fmaf(x3.z, wr[14], a); a = fmaf(x3.w, wr[15], a);
}

// scalar LN for the self-check path
__device__ void ln_scalar(const float* x, float* o,
                          const float* g, const float* bb) {
    float mu = 0.f;
    for (int i = 0; i < ND; i++) mu += x[i];
    mu *= (1.f / 64.f);
    float var = 0.f;
    for (int i = 0; i < ND; i++) { float d = x[i] - mu; var += d * d; }
    var *= (1.f / 64.f);
    float rstd = rsqrtf(var + 1e-5f);
    for (int i = 0; i < ND; i++) o[i] = (x[i] - mu) * rstd * g[i] + bb[i];
}

// H0 interpretation (as the shown reference): weights stored (in,out),
// y = x @ W. Output: fp32 logits [B*T, V] then fp32 loss.
__global__ __launch_bounds__(1024, 4) void gpt_fwd(
    const float* __restrict__ W, const void* __restrict__ idxp,
    const void* __restrict__ tgtp, float* __restrict__ out,
    float* __restrict__ loss_acc, const int* __restrict__ flags)
{
    __shared__ alignas(16) float xs[NT][68];           // residual stream
    __shared__ alignas(16) float xn[NT][68];           // LN out / attn out
    __shared__ alignas(16) unsigned short qs[NT][72];
    __shared__ alignas(16) unsigned short ks[NT][72];
    __shared__ alignas(16) unsigned short vs[NT][72];
    __shared__ alignas(16) float hch[32][264];         // FFN hidden chunk (32 rows)
    __shared__ float wsum[16];

    const int tid  = threadIdx.x;
    const int lane = tid & 63;
    const int wave = tid >> 6;                         // 0..15
    const int b    = blockIdx.x;
    const bool i64 = !(*flags & 4);
    const int*       idx32 = (const int*)idxp;
    const long long* idx64 = (const long long*)idxp;
    const int*       tgt32 = (const int*)tgtp;
    const long long* tgt64 = (const long long*)tgtp;

    // ---- embed: x = tok_emb[idx] + pos_emb (float4, 2 iters/thread) ----
    for (int e = tid * 4; e < NT * ND; e += 4096) {
        int r = e >> 6, c = e & 63;
        int n = b * NT + r;
        int tok = i64 ? (int)idx64[n] : idx32[n];
        float4 te = *(const float4*)&W[OFF_TOK + tok * ND + c];
        float4 pe = *(const float4*)&W[OFF_POS + r * ND + c];
        float4 xv;
        xv.x = te.x + pe.x; xv.y = te.y + pe.y;
        xv.z = te.z + pe.z; xv.w = te.w + pe.w;
        *(float4*)&xs[r][c] = xv;
    }
    __syncthreads();

    for (int l = 0; l < NL; l++) {
        ln_helper(xs, xn, W + OFF_LN1G + l * ND, W + OFF_LN1B + l * ND, tid);
        __syncthreads();

        // ---- QKV: wave owns 8 rows; weight columns cached in registers ----
        {
            #pragma unroll 1
            for (int mmat = 0; mmat < 3; mmat++) {
                const float* wm = W + (mmat == 0 ? OFF_WQ : (mmat == 1 ? OFF_WK : OFF_WV))
                                    + l * ND * ND;
                unsigned short (*dstp)[72] = (mmat == 0) ? qs : ((mmat == 1) ? ks : vs);
                float acc[8];
                #pragma unroll
                for (int rr = 0; rr < 8; rr++) acc[rr] = 0.f;
                #pragma unroll 1
                for (int ih = 0; ih < 4; ih++) {
                    float wr[16];
                    #pragma unroll
                    for (int i = 0; i < 16; i++) wr[i] = wm[(ih * 16 + i) * ND + lane];
                    #pragma unroll
                    for (int rr = 0; rr < 8; rr++)
                        fma16(&xn[wave * 8 + rr][ih * 16], wr, acc[rr]);
                }
                #pragma unroll
                for (int rr = 0; rr < 8; rr++)
                    dstp[wave * 8 + rr][lane] = f2bf(acc[rr]);
            }
        }
        __syncthreads();

        // ---- attention: wave = (head, half); 8-key chunks break the dep chain ----
        {
            const int h8 = (wave >> 1) * 8;
            const int r  = lane + (wave & 1) * 64;
            const float scale = 0.35355339059327373f;   // 1/sqrt(8)
            float qv[8];
            uint4 qq = *(const uint4*)&qs[r][h8];
            unpack8(qq, qv);
            #pragma unroll
            for (int d = 0; d < 8; d++) qv[d] *= scale;
            float m = -1e30f, lsum = 0.f;
            float o[8] = {0, 0, 0, 0, 0, 0, 0, 0};
            for (int base = 0; base <= r; base += 8) {
                float sc[8];
                #pragma unroll
                for (int t = 0; t < 8; t++) {
                    int kk = base + t; kk = kk > 127 ? 127 : kk;
                    uint4 kr = *(const uint4*)&ks[kk][h8];
                    float kf[8]; unpack8(kr, kf);
                    float s = 0.f;
                    #pragma unroll
                    for (int d = 0; d < 8; d++) s = fmaf(qv[d], kf[d], s);
                    sc[t] = (base + t <= r) ? s : -1e30f;
                }
                float cm = fmaxf(fmaxf(fmaxf(sc[0], sc[1]), fmaxf(sc[2], sc[3])),
                                 fmaxf(fmaxf(sc[4], sc[5]), fmaxf(sc[6], sc[7])));
                float nm  = fmaxf(m, cm);
                float fac = __expf(m - nm);
                lsum *= fac;
                #pragma unroll
                for (int d = 0; d < 8; d++) o[d] *= fac;
                #pragma unroll
                for (int t = 0; t < 8; t++) {
                    float p = __expf(sc[t] - nm);        // masked lanes: exp(-1e30)=0
                    int kk = base + t; kk = kk > 127 ? 127 : kk;
                    uint4 vr = *(const uint4*)&vs[kk][h8];
                    float vf[8]; unpack8(vr, vf);
                    lsum += p;
                    #pragma unroll
                    for (int d = 0; d < 8; d++) o[d] = fmaf(p, vf[d], o[d]);
                }
                m = nm;
            }
            float inv = 1.f / lsum;
            #pragma unroll
            for (int d = 0; d < 8; d++) xn[r][h8 + d] = o[d] * inv;
        }
        __syncthreads();

        // ---- out projection + residual (cached weight columns) ----
        {
            const float* wo = W + OFF_WO + l * ND * ND;
            float acc[8];
            #pragma unroll
            for (int rr = 0; rr < 8; rr++) acc[rr] = W[OFF_BO + l * ND + lane];
            #pragma unroll 1
            for (int ih = 0; ih < 4; ih++) {
                float wr[16];
                #pragma unroll
                for (int i = 0; i < 16; i++) wr[i] = wo[(ih * 16 + i) * ND + lane];
                #pragma unroll
                for (int rr = 0; rr < 8; rr++)
                    fma16(&xn[wave * 8 + rr][ih * 16], wr, acc[rr]);
            }
            #pragma unroll
            for (int rr = 0; rr < 8; rr++)
                xs[wave * 8 + rr][lane] += acc[rr];
        }
        __syncthreads();

        ln_helper(xs, xn, W + OFF_LN2G + l * ND, W + OFF_LN2B + l * ND, tid);
        __syncthreads();

        // ---- FFN in 32-row chunks ----
        {
            const float* w1 = W + OFF_W1 + l * ND * NDF;
            const float* w2 = W + OFF_W2 + l * NDF * ND;
            const float* b1 = W + OFF_B1 + l * NDF;
            const float* b2 = W + OFF_B2 + l * ND;
            for (int ch = 0; ch < 4; ch++) {
                int rbase = ch * 32;
                {   // F1: thread = (row lr, 8 cols at j0)
                    int lr = tid >> 5;
                    int j0 = (tid & 31) * 8;
                    int r  = rbase + lr;
                    float4 ba  = *(const float4*)(b1 + j0);
                    float4 bb4 = *(const float4*)(b1 + j0 + 4);
                    float a0 = ba.x,  a1 = ba.y,  a2 = ba.z,  a3 = ba.w;
                    float a4 = bb4.x, a5 = bb4.y, a6 = bb4.z, a7 = bb4.w;
                    #pragma unroll 4
                    for (int i4 = 0; i4 < ND; i4 += 4) {
                        float4 xv = *(const float4*)&xn[r][i4];
                        #pragma unroll
                        for (int s = 0; s < 4; s++) {
                            float xvs = (s == 0) ? xv.x : (s == 1) ? xv.y
                                      : (s == 2) ? xv.z : xv.w;
                            float4 wa = *(const float4*)(w1 + (i4 + s) * NDF + j0);
                            float4 wb = *(const float4*)(w1 + (i4 + s) * NDF + j0 + 4);
                            a0 = fmaf(xvs, wa.x, a0); a1 = fmaf(xvs, wa.y, a1);
                            a2 = fmaf(xvs, wa.z, a2); a3 = fmaf(xvs, wa.w, a3);
                            a4 = fmaf(xvs, wb.x, a4); a5 = fmaf(xvs, wb.y, a5);
                            a6 = fmaf(xvs, wb.z, a6); a7 = fmaf(xvs, wb.w, a7);
                        }
                    }
                    float4 h0, h1;
                    h0.x = fmaxf(a0, 0.f); h0.y = fmaxf(a1, 0.f);
                    h0.z = fmaxf(a2, 0.f); h0.w = fmaxf(a3, 0.f);
                    h1.x = fmaxf(a4, 0.f); h1.y = fmaxf(a5, 0.f);
                    h1.z = fmaxf(a6, 0.f); h1.w = fmaxf(a7, 0.f);
                    *(float4*)&hch[lr][j0]     = h0;
                    *(float4*)&hch[lr][j0 + 4] = h1;
                }
                __syncthreads();
                {   // F2: thread = (row lr, 2 cols at i0)
                    int lr = tid >> 5;
                    int i0 = (tid & 31) * 2;
                    int r  = rbase + lr;
                    float a0 = 0.f, a1 = 0.f;
                    #pragma unroll 4
                    for (int j4 = 0; j4 < NDF; j4 += 4) {
                        float4 hv = *(const float4*)&hch[lr][j4];
                        #pragma unroll
                        for (int s = 0; s < 4; s++) {
                            float hvs = (s == 0) ? hv.x : (s == 1) ? hv.y
                                      : (s == 2) ? hv.z : hv.w;
                            float2 w = *(const float2*)(w2 + (j4 + s) * ND + i0);
                            a0 = fmaf(hvs, w.x, a0); a1 = fmaf(hvs, w.y, a1);
                        }
                    }
                    float2 bb2 = *(const float2*)(b2 + i0);
                    xs[r][i0]     += a0 + bb2.x;
                    xs[r][i0 + 1] += a1 + bb2.y;
                }
                __syncthreads();
            }
        }
    }

    ln_helper(xs, xn, W + OFF_LNFG, W + OFF_LNFB, tid);
    __syncthreads();

    // ---- logits (fp32) + loss: wave owns 8 rows ----
    {
        const float* lmw = W + OFF_LMW;
        float wacc = 0.f;
        for (int rr = 0; rr < 8; rr++) {
            int r = wave * 8 + rr;
            float lg  = W[OFF_LMB + lane];
            float lg2 = W[OFF_LMB + 64];
            #pragma unroll 8
            for (int i = 0; i < ND; i++) {
                float xv = xn[r][i];
                lg  = fmaf(xv, lmw[i * NV + lane], lg);
                lg2 = fmaf(xv, lmw[i * NV + 64],  lg2);
            }
            float M = lg;
            #pragma unroll
            for (int off = 32; off; off >>= 1) M = fmaxf(M, __shfl_xor(M, off));
            M = fmaxf(M, lg2);
            float ssum = __expf(lg - M);
            #pragma unroll
            for (int off = 32; off; off >>= 1) ssum += __shfl_xor(ssum, off);
            ssum += __expf(lg2 - M);
            float lse = M + logf(ssum);
            int row = b * NT + r;
            int tg  = i64 ? (int)tgt64[row] : tgt32[row];
            float lt = (tg < 64) ? __shfl(lg, tg) : lg2;
            wacc += lt - lse;
            out[row * NV + lane] = lg;
            if (lane == 0) out[row * NV + 64] = lg2;
        }
        if (lane == 0) wsum[wave] = wacc;
        __syncthreads();
        if (tid == 0) {
            float t = 0.f;
            #pragma unroll
            for (int w = 0; w < 16; w++) t += wsum[w];
            atomicAdd(loss_acc, t);
        }
    }
    __syncthreads();

    // ---- self-check: block 0 thread 0 recomputes row 0 logits (attn = v0) ----
    if (b == 0 && tid == 0) {
        float x0[ND], xn0[ND], v0[ND], h0[NDF];
        int tok0 = i64 ? (int)idx64[0] : idx32[0];
        for (int c = 0; c < ND; c++)
            x0[c] = W[OFF_TOK + tok0 * ND + c] + W[OFF_POS + c];
        for (int l = 0; l < NL; l++) {
            ln_scalar(x0, xn0, W + OFF_LN1G + l * ND, W + OFF_LN1B + l * ND);
            for (int c = 0; c < ND; c++) {
                float a = 0.f;
                for (int i = 0; i < ND; i++)
                    a += xn0[i] * W[OFF_WV + l * ND * ND + i * ND + c];
                v0[c] = a;
            }
            for (int c = 0; c < ND; c++) {
                float a = W[OFF_BO + l * ND + c];
                for (int i = 0; i < ND; i++)
                    a += v0[i] * W[OFF_WO + l * ND * ND + i * ND + c];
                x0[c] += a;
            }
            ln_scalar(x0, xn0, W + OFF_LN2G + l * ND, W + OFF_LN2B + l * ND);
            for (int j = 0; j < NDF; j++) {
                float a = W[OFF_B1 + l * NDF + j];
                for (int i = 0; i < ND; i++)
                    a += xn0[i] * W[OFF_W1 + l * ND * NDF + i * NDF + j];
                h0[j] = fmaxf(a, 0.f);
            }
            for (int c = 0; c < ND; c++) {
                float a = W[OFF_B2 + l * ND + c];
                for (int j = 0; j < NDF; j++)
                    a += h0[j] * W[OFF_W2 + l * NDF * ND + j * ND + c];
                x0[c] += a;
            }
        }
        ln_scalar(x0, xn0, W + OFF_LNFG, W + OFF_LNFB);
        bool bad = false;
        for (int v = 0; v < NV; v++) {
            float lg = W[OFF_LMB + v];
            for (int i = 0; i < ND; i++)
                lg += xn0[i] * W[OFF_LMW + i * NV + v];
            if (!(fabsf(out[v] - lg) <= 0.05f)) bad = true;   // catches NaN
        }
        if (bad) out[0] = 100.0f;
    }
}

__global__ void finalize_loss(const float* __restrict__ acc,
                              float* __restrict__ out) {
    out[NBT * NV] = -acc[0] * (1.f / (float)NBT);
}

extern "C" void kernel_launch(void* const* d_in, const int* in_sizes, int n_in,
                              void* d_out, int out_size, void* d_ws, size_t ws_size,
                              hipStream_t stream)
{
    static const int want[21] = {4160, 8192, 192, 192, 12288, 12288, 12288,
                                 12288, 192, 192, 192, 49152, 768, 49152, 192,
                                 64, 64, 4160, 65, 524288, 524288};
    int diag = 0;
    if (n_in != 21) diag = 3;
    else for (int i = 0; i < 21; i++) if (in_sizes[i] != want[i]) { diag = 3; break; }
    if (!diag && out_size != NBT * NV + 1) diag = 4;
    if (!diag && ws_size < (size_t)(OFF_FLAG + 1) * 4) diag = 5;
    if (diag) {
        diag_fill<<<(out_size + 255) / 256, 256, 0, stream>>>(
            (float*)d_out, out_size, (float)diag);
        return;
    }

    float* W = (float*)d_ws;
    float* loss_acc = W + OFF_LOSS;
    int*   flags    = (int*)(W + OFF_FLAG);
    hipMemsetAsync(W + OFF_LOSS, 0, 2 * sizeof(float), stream);

    detect_float<<<1, 256, 0, stream>>>((const unsigned short*)d_in[0], flags);
    detect_int  <<<1, 256, 0, stream>>>((const int*)d_in[19], flags);

    CvtArgs a;
    for (int i = 0; i < 19; i++) a.p[i] = d_in[i];
    cvt_params<<<(CVT_TOTAL + 255) / 256, 256, 0, stream>>>(a, W, flags);

    gpt_fwd<<<NB, 1024, 0, stream>>>(W, d_in[19], d_in[20],
                                     (float*)d_out, loss_acc, flags);
    finalize_loss<<<1, 1, 0, stream>>>(loss_acc, (float*)d_out);
}

// Round 2
// 2776.492 us; speedup vs baseline: 5.3579x; 4.4128x over previous
//
#include <hip/hip_runtime.h>
#include <hip/hip_bf16.h>

#define NB  4096
#define NT  128
#define ND  64
#define NV  65
#define NL  3
#define NH  8
#define NDF 256
#define NBT (NB*NT)

// fp32 param offsets inside d_ws (element counts)
#define OFF_TOK   0
#define OFF_POS   4160
#define OFF_LN1G  12352
#define OFF_LN1B  12544
#define OFF_WQ    12736
#define OFF_WK    25024
#define OFF_WV    37312
#define OFF_WO    49600
#define OFF_BO    61888
#define OFF_LN2G  62080
#define OFF_LN2B  62272
#define OFF_W1    62464
#define OFF_B1    111616
#define OFF_W2    112384
#define OFF_B2    161536
#define OFF_LNFG  161728
#define OFF_LNFB  161792
#define OFF_LMW   161856
#define OFF_LMB   166016
#define CVT_TOTAL 166081
#define OFF_LOSS  166144   // fp32 loss accumulator slot
#define OFF_FLAG  166145   // flags: bit0 fp32 floats; bit2 int32 ints; bit3 MFMA-layout-BAD

// packed bf16 weights (hi + lo) appended after flag, 16B aligned
#define PKF       166148            // float offset of packed region
#define PK_ELEMS  147456            // bf16 elements per copy (hi), lo mirrors at +PK_ELEMS
#define NEED_WS   ((size_t)(PKF + PK_ELEMS) * 4)   // lo+hi = PK_ELEMS floats total

typedef short s8v  __attribute__((ext_vector_type(8)));
typedef float f4v  __attribute__((ext_vector_type(4)));

struct CvtArgs { const void* p[19]; };

__device__ __forceinline__ unsigned short f2bf(float x) {
    unsigned int u = __float_as_uint(x);
    u = (u + 0x7fffu + ((u >> 16) & 1u)) >> 16;   // RNE
    return (unsigned short)u;
}
__device__ __forceinline__ float bf2f(unsigned short h) {
    return __uint_as_float(((unsigned int)h) << 16);
}
__device__ __forceinline__ f4v mfma16(s8v a, s8v b, f4v c) {
    return __builtin_amdgcn_mfma_f32_16x16x32_bf16(a, b, c, 0, 0, 0);
}

__global__ void diag_fill(float* __restrict__ out, int n, float val) {
    int i = blockIdx.x * 256 + threadIdx.x;
    if (i < n) out[i] = val;
}

__global__ void detect_float(const unsigned short* __restrict__ tok,
                             int* __restrict__ flags) {
    int bad = 0;
    for (int i = threadIdx.x; i < 4096; i += 256) {
        float v = __uint_as_float(((unsigned int)tok[i]) << 16);
        if (!(fabsf(v) < 1000.f)) bad = 1;
    }
    if (bad) atomicOr(flags, 1);
}

__global__ void detect_int(const int* __restrict__ idx32,
                           int* __restrict__ flags) {
    int proven = 0;
    #pragma unroll
    for (int j = 0; j < 8; j++) {
        int slot = 2 * (threadIdx.x * 8 + j) + 1;
        if (idx32[slot] != 0) proven = 1;
    }
    if (proven) atomicOr(flags, 4);
}

// param conversion (bf16 or fp32 -> fp32) into workspace
__global__ void cvt_params(CvtArgs a, float* __restrict__ W,
                           const int* __restrict__ flags) {
    int tid = blockIdx.x * 256 + threadIdx.x;
    if (tid >= CVT_TOTAL) return;
    const int offs[20] = {0,4160,12352,12544,12736,25024,37312,49600,61888,
                          62080,62272,62464,111616,112384,161536,161728,
                          161792,161856,166016,166081};
    int s = 0;
    #pragma unroll
    for (int k = 1; k < 19; k++) s += (tid >= offs[k]);
    int local = tid - offs[s];
    if (*flags & 1) {
        W[tid] = ((const float*)a.p[s])[local];
    } else {
        unsigned int v = ((const unsigned short*)a.p[s])[local];
        W[tid] = __uint_as_float(v << 16);
    }
}

// Pack matmul weights into MFMA b-frag order, hi+lo bf16.
// Fragment model (B operand of mfma_f32_16x16x32_bf16):
//   lane l, elem e holds B[kt*32 + (l>>4)*8 + e][nt*16 + (l&15)]
// Tile order t = nt*KT + kt; element p enumerates [group][layer][t][l][e].
__global__ void pack_weights(const float* __restrict__ W,
                             unsigned short* __restrict__ pkw) {
    int p = blockIdx.x * 256 + threadIdx.x;
    if (p >= PK_ELEMS) return;
    int srcoff, K, N, perlay, local, ktbits;
    if (p < 49152) {
        int grp = p / 12288; local = p % 12288;
        srcoff = (grp == 0) ? OFF_WQ : (grp == 1) ? OFF_WK
               : (grp == 2) ? OFF_WV : OFF_WO;
        K = 64; N = 64; perlay = 4096; ktbits = 1;
    } else if (p < 98304) {
        local = p - 49152; srcoff = OFF_W1; K = 64; N = 256;
        perlay = 16384; ktbits = 1;
    } else {
        local = p - 98304; srcoff = OFF_W2; K = 256; N = 64;
        perlay = 16384; ktbits = 3;
    }
    int lay = local / perlay, rem = local % perlay;
    int t = rem >> 9, le = rem & 511, l = le >> 3, e = le & 7;
    int kt = t & ((1 << ktbits) - 1), nt = t >> ktbits;
    int row = kt * 32 + (l >> 4) * 8 + e;
    int col = nt * 16 + (l & 15);
    float v = W[srcoff + lay * K * N + row * N + col];
    unsigned short hi = f2bf(v);
    pkw[p] = hi;
    pkw[PK_ELEMS + p] = f2bf(v - bf2f(hi));
}

// Verify assumed A/B operand layout against the HW-verified C/D layout using
// asymmetric exact-integer matrices. On mismatch set flags bit3 -> VALU path.
__global__ void mfma_probe(int* __restrict__ flags) {
    int l = threadIdx.x;
    s8v av, bv;
    int i = l & 15;
    #pragma unroll
    for (int e = 0; e < 8; e++) {
        int k = (l >> 4) * 8 + e;
        av[e] = (short)f2bf((float)(((i * 5 + k * 3) & 7) - 3));
        bv[e] = (short)f2bf((float)(((k * 7 + i * 11) & 7) - 4));
    }
    f4v c = {0.f, 0.f, 0.f, 0.f};
    c = mfma16(av, bv, c);
    int bad = 0;
    #pragma unroll
    for (int reg = 0; reg < 4; reg++) {
        int row = (l >> 4) * 4 + reg, col = l & 15;
        float exp = 0.f;
        for (int k = 0; k < 32; k++)
            exp += (float)(((row * 5 + k * 3) & 7) - 3) *
                   (float)(((k * 7 + col * 11) & 7) - 4);
        if (c[reg] != exp) bad = 1;
    }
    if (bad) atomicOr(flags, 8);
}

__device__ __forceinline__ void unpack8(uint4 u, float* f) {
    f[0] = __uint_as_float(u.x << 16); f[1] = __uint_as_float(u.x & 0xffff0000u);
    f[2] = __uint_as_float(u.y << 16); f[3] = __uint_as_float(u.y & 0xffff0000u);
    f[4] = __uint_as_float(u.z << 16); f[5] = __uint_as_float(u.z & 0xffff0000u);
    f[6] = __uint_as_float(u.w << 16); f[7] = __uint_as_float(u.w & 0xffff0000u);
}

// LayerNorm over D=64, 8 threads per row, fp32 row-major output
__device__ __forceinline__ void ln_rm(const float (*src)[68], float (*dst)[68],
                                      const float* __restrict__ g,
                                      const float* __restrict__ bb, int tid) {
    int r = tid >> 3, q = tid & 7;
    int c0 = q * 8;
    float s = 0.f, s2 = 0.f;
    #pragma unroll
    for (int c = 0; c < 8; c++) { float v = src[r][c0 + c]; s += v; s2 += v * v; }
    s += __shfl_xor(s, 1);  s2 += __shfl_xor(s2, 1);
    s += __shfl_xor(s, 2);  s2 += __shfl_xor(s2, 2);
    s += __shfl_xor(s, 4);  s2 += __shfl_xor(s2, 4);
    float mu   = s  * (1.f / 64.f);
    float var  = s2 * (1.f / 64.f) - mu * mu;
    float rstd = rsqrtf(var + 1e-5f);
    #pragma unroll
    for (int c = 0; c < 8; c++) {
        int cc = c0 + c;
        dst[r][cc] = (src[r][cc] - mu) * rstd * g[cc] + bb[cc];
    }
}

// LayerNorm writing hi/lo bf16 a-frag layout: element (r,col) at
// ((  (r>>4)*2 + (col>>5) )*64 + ((col>>3)&3)*16 + (r&15))*8 + (col&7)
__device__ __forceinline__ void ln_frag(const float (*src)[68],
        unsigned short* __restrict__ dhi, unsigned short* __restrict__ dlo,
        const float* __restrict__ g, const float* __restrict__ bb, int tid) {
    int r = tid >> 3, q = tid & 7, c0 = q * 8;
    float s = 0.f, s2 = 0.f;
    #pragma unroll
    for (int c = 0; c < 8; c++) { float v = src[r][c0 + c]; s += v; s2 += v * v; }
    s += __shfl_xor(s, 1);  s2 += __shfl_xor(s2, 1);
    s += __shfl_xor(s, 2);  s2 += __shfl_xor(s2, 2);
    s += __shfl_xor(s, 4);  s2 += __shfl_xor(s2, 4);
    float mu   = s  * (1.f / 64.f);
    float var  = s2 * (1.f / 64.f) - mu * mu;
    float rstd = rsqrtf(var + 1e-5f);
    unsigned uh[4], ul[4];
    #pragma unroll
    for (int c2 = 0; c2 < 4; c2++) {
        float y0 = (src[r][c0 + c2*2    ] - mu) * rstd * g[c0 + c2*2    ] + bb[c0 + c2*2    ];
        float y1 = (src[r][c0 + c2*2 + 1] - mu) * rstd * g[c0 + c2*2 + 1] + bb[c0 + c2*2 + 1];
        unsigned short h0 = f2bf(y0), h1 = f2bf(y1);
        uh[c2] = (unsigned)h0 | ((unsigned)h1 << 16);
        ul[c2] = (unsigned)f2bf(y0 - bf2f(h0)) | ((unsigned)f2bf(y1 - bf2f(h1)) << 16);
    }
    int di = (((r >> 4) * 2 + (q >> 2)) * 64 + (q & 3) * 16 + (r & 15)) * 8;
    *(uint4*)(dhi + di) = make_uint4(uh[0], uh[1], uh[2], uh[3]);
    *(uint4*)(dlo + di) = make_uint4(ul[0], ul[1], ul[2], ul[3]);
}

// 16 FMAs of one activation row segment against cached weights (VALU path)
__device__ __forceinline__ void fma16(const float* xr, const float* wr, float& a) {
    float4 x0 = *(const float4*)(xr);
    float4 x1 = *(const float4*)(xr + 4);
    float4 x2 = *(const float4*)(xr + 8);
    float4 x3 = *(const float4*)(xr + 12);
    a = fmaf(x0.x, wr[0],  a); a = fmaf(x0.y, wr[1],  a);
    a = fmaf(x0.z, wr[2],  a); a = fmaf(x0.w, wr[3],  a);
    a = fmaf(x1.x, wr[4],  a); a = fmaf(x1.y, wr[5],  a);
    a = fmaf(x1.z, wr[6],  a); a = fmaf(x1.w, wr[7],  a);
    a = fmaf(x2.x, wr[8],  a); a = fmaf(x2.y, wr[9],  a);
    a = fmaf(x2.z, wr[10], a); a = fmaf(x2.w, wr[11], a);
    a = fmaf(x3.x, wr[12], a); a = fmaf(x3.y, wr[13], a);
    a = fmaf(x3.z, wr[14], a); a = fmaf(x3.w, wr[15], a);
}

// scalar LN for the self-check path
__device__ void ln_scalar(const float* x, float* o,
                          const float* g, const float* bb) {
    float mu = 0.f;
    for (int i = 0; i < ND; i++) mu += x[i];
    mu *= (1.f / 64.f);
    float var = 0.f;
    for (int i = 0; i < ND; i++) { float d = x[i] - mu; var += d * d; }
    var *= (1.f / 64.f);
    float rstd = rsqrtf(var + 1e-5f);
    for (int i = 0; i < ND; i++) o[i] = (x[i] - mu) * rstd * g[i] + bb[i];
}

__global__ __launch_bounds__(1024, 4) void gpt_fwd(
    const float* __restrict__ W, const unsigned short* __restrict__ pkw,
    int usepk, const void* __restrict__ idxp, const void* __restrict__ tgtp,
    float* __restrict__ out, float* __restrict__ loss_acc,
    const int* __restrict__ flags)
{
    __shared__ alignas(16) float xs[NT][68];          // residual (34.8KB)
    __shared__ alignas(16) unsigned char regB[34816]; // xah+xal frags OR xnR fp32
    __shared__ alignas(16) unsigned char uni[65536];  // qkv OR hidden-frags OR v1-hch
    __shared__ float wsum[16];

    float (*xnR)[68] = (float (*)[68])regB;
    unsigned short* xah = (unsigned short*)regB;            // [8mt][2kt][64][8]
    unsigned short* xal = (unsigned short*)(regB + 16384);
    unsigned short (*qs)[72] = (unsigned short (*)[72])(uni);
    unsigned short (*ks)[72] = (unsigned short (*)[72])(uni + 18432);
    unsigned short (*vs)[72] = (unsigned short (*)[72])(uni + 36864);
    unsigned short* ha = (unsigned short*)uni;              // [4mt][8kt][64][8]
    unsigned short* hl = (unsigned short*)(uni + 32768);
    float (*hch)[264] = (float (*)[264])uni;                // VALU-path hidden

    const int tid  = threadIdx.x;
    const int lane = tid & 63;
    const int w    = tid >> 6;                              // 0..15
    const int b    = blockIdx.x;
    const int fl   = *flags;
    const bool i64 = !(fl & 4);
    const bool use_mfma = usepk && !(fl & 8);
    const int*       idx32 = (const int*)idxp;
    const long long* idx64 = (const long long*)idxp;
    const int*       tgt32 = (const int*)tgtp;
    const long long* tgt64 = (const long long*)tgtp;

    // ---- embed: x = tok_emb[idx] + pos_emb ----
    for (int e = tid * 4; e < NT * ND; e += 4096) {
        int r = e >> 6, c = e & 63;
        int n = b * NT + r;
        int tok = i64 ? (int)idx64[n] : idx32[n];
        float4 te = *(const float4*)&W[OFF_TOK + tok * ND + c];
        float4 pe = *(const float4*)&W[OFF_POS + r * ND + c];
        float4 xv;
        xv.x = te.x + pe.x; xv.y = te.y + pe.y;
        xv.z = te.z + pe.z; xv.w = te.w + pe.w;
        *(float4*)&xs[r][c] = xv;
    }
    __syncthreads();

    if (use_mfma) {
        // ================= MFMA path =================
        for (int lay = 0; lay < NL; lay++) {
            ln_frag(xs, xah, xal, W + OFF_LN1G + lay * 64, W + OFF_LN1B + lay * 64, tid);
            __syncthreads();

            // ---- QKV: 96 tiles (mat,mt,nt), 6 per wave ----
            {
                const unsigned short* pbase = pkw + lay * 4096;
                #pragma unroll 1
                for (int i = 0; i < 6; i++) {
                    int ft = w * 6 + i;
                    int mat = ft >> 5, mt = (ft >> 2) & 7, nt = ft & 3;
                    const unsigned short* pb = pbase + mat * 12288 + nt * 1024 + lane * 8;
                    f4v acc = {0.f, 0.f, 0.f, 0.f};
                    #pragma unroll
                    for (int kt = 0; kt < 2; kt++) {
                        s8v ah = *(const s8v*)(xah + ((mt * 2 + kt) * 64 + lane) * 8);
                        s8v al = *(const s8v*)(xal + ((mt * 2 + kt) * 64 + lane) * 8);
                        s8v bh = *(const s8v*)(pb + kt * 512);
                        s8v bl = *(const s8v*)(pb + PK_ELEMS + kt * 512);
                        acc = mfma16(ah, bh, acc);
                        acc = mfma16(ah, bl, acc);
                        acc = mfma16(al, bh, acc);
                    }
                    unsigned short (*dst)[72] = (mat == 0) ? qs : (mat == 1) ? ks : vs;
                    int row0 = mt * 16 + (lane >> 4) * 4, col = nt * 16 + (lane & 15);
                    dst[row0    ][col] = f2bf(acc[0]);
                    dst[row0 + 1][col] = f2bf(acc[1]);
                    dst[row0 + 2][col] = f2bf(acc[2]);
                    dst[row0 + 3][col] = f2bf(acc[3]);
                }
            }
            __syncthreads();

            // ---- attention (VALU); out -> xah/xal frags ----
            {
                const int head = w & 7, hh = w >> 3;      // 2 light + 2 heavy per SIMD
                const int h8 = head * 8;
                const int r  = lane + hh * 64;
                const float scale = 0.35355339059327373f;
                float qv[8];
                uint4 qq = *(const uint4*)&qs[r][h8];
                unpack8(qq, qv);
                #pragma unroll
                for (int d = 0; d < 8; d++) qv[d] *= scale;
                float m = -1e30f, lsum = 0.f;
                float o[8] = {0, 0, 0, 0, 0, 0, 0, 0};
                for (int base = 0; base <= r; base += 8) {
                    float sc[8];
                    #pragma unroll
                    for (int t = 0; t < 8; t++) {
                        int kk = base + t; kk = kk > 127 ? 127 : kk;
                        uint4 kr = *(const uint4*)&ks[kk][h8];
                        float kf[8]; unpack8(kr, kf);
                        float s = 0.f;
                        #pragma unroll
                        for (int d = 0; d < 8; d++) s = fmaf(qv[d], kf[d], s);
                        sc[t] = (base + t <= r) ? s : -1e30f;
                    }
                    float cm = fmaxf(fmaxf(fmaxf(sc[0], sc[1]), fmaxf(sc[2], sc[3])),
                                     fmaxf(fmaxf(sc[4], sc[5]), fmaxf(sc[6], sc[7])));
                    float nm  = fmaxf(m, cm);
                    float fac = __expf(m - nm);
                    lsum *= fac;
                    #pragma unroll
                    for (int d = 0; d < 8; d++) o[d] *= fac;
                    #pragma unroll
                    for (int t = 0; t < 8; t++) {
                        float p = __expf(sc[t] - nm);
                        int kk = base + t; kk = kk > 127 ? 127 : kk;
                        uint4 vr = *(const uint4*)&vs[kk][h8];
                        float vf[8]; unpack8(vr, vf);
                        lsum += p;
                        #pragma unroll
                        for (int d = 0; d < 8; d++) o[d] = fmaf(p, vf[d], o[d]);
                    }
                    m = nm;
                }
                float inv = 1.f / lsum;
                float y[8];
                #pragma unroll
                for (int d = 0; d < 8; d++) y[d] = o[d] * inv;
                unsigned uh[4], ul[4];
                #pragma unroll
                for (int c2 = 0; c2 < 4; c2++) {
                    unsigned short h0 = f2bf(y[c2*2]), h1 = f2bf(y[c2*2+1]);
                    uh[c2] = (unsigned)h0 | ((unsigned)h1 << 16);
                    ul[c2] = (unsigned)f2bf(y[c2*2]   - bf2f(h0)) |
                             ((unsigned)f2bf(y[c2*2+1] - bf2f(h1)) << 16);
                }
                int di = (((r >> 4) * 2 + (head >> 2)) * 64 + (head & 3) * 16 + (r & 15)) * 8;
                *(uint4*)(xah + di) = make_uint4(uh[0], uh[1], uh[2], uh[3]);
                *(uint4*)(xal + di) = make_uint4(ul[0], ul[1], ul[2], ul[3]);
            }
            __syncthreads();

            // ---- WO: 32 tiles, 2 per wave; D += xs ----
            {
                const unsigned short* pbase = pkw + 36864 + lay * 4096;
                const float* bo = W + OFF_BO + lay * 64;
                #pragma unroll 1
                for (int i = 0; i < 2; i++) {
                    int ft = w * 2 + i;
                    int mt = ft >> 2, nt = ft & 3;
                    const unsigned short* pb = pbase + nt * 1024 + lane * 8;
                    f4v acc = {0.f, 0.f, 0.f, 0.f};
                    #pragma unroll
                    for (int kt = 0; kt < 2; kt++) {
                        s8v ah = *(const s8v*)(xah + ((mt * 2 + kt) * 64 + lane) * 8);
                        s8v al = *(const s8v*)(xal + ((mt * 2 + kt) * 64 + lane) * 8);
                        s8v bh = *(const s8v*)(pb + kt * 512);
                        s8v bl = *(const s8v*)(pb + PK_ELEMS + kt * 512);
                        acc = mfma16(ah, bh, acc);
                        acc = mfma16(ah, bl, acc);
                        acc = mfma16(al, bh, acc);
                    }
                    int row0 = mt * 16 + (lane >> 4) * 4, col = nt * 16 + (lane & 15);
                    float bias = bo[col];
                    xs[row0    ][col] += acc[0] + bias;
                    xs[row0 + 1][col] += acc[1] + bias;
                    xs[row0 + 2][col] += acc[2] + bias;
                    xs[row0 + 3][col] += acc[3] + bias;
                }
            }
            __syncthreads();

            ln_frag(xs, xah, xal, W + OFF_LN2G + lay * 64, W + OFF_LN2B + lay * 64, tid);
            __syncthreads();

            // ---- FFN in 64-row halves ----
            for (int hh = 0; hh < 2; hh++) {
                {   // F1: 64 tiles, 4 per wave; relu -> hidden frags
                    const float* b1 = W + OFF_B1 + lay * 256;
                    #pragma unroll 1
                    for (int i = 0; i < 4; i++) {
                        int ft = w * 4 + i;
                        int mtl = ft >> 4, nt = ft & 15;
                        int mt = hh * 4 + mtl;
                        const unsigned short* pb = pkw + 49152 + lay * 16384 + nt * 1024 + lane * 8;
                        f4v acc = {0.f, 0.f, 0.f, 0.f};
                        #pragma unroll
                        for (int kt = 0; kt < 2; kt++) {
                            s8v ah = *(const s8v*)(xah + ((mt * 2 + kt) * 64 + lane) * 8);
                            s8v al = *(const s8v*)(xal + ((mt * 2 + kt) * 64 + lane) * 8);
                            s8v bh = *(const s8v*)(pb + kt * 512);
                            s8v bl = *(const s8v*)(pb + PK_ELEMS + kt * 512);
                            acc = mfma16(ah, bh, acc);
                            acc = mfma16(ah, bl, acc);
                            acc = mfma16(al, bh, acc);
                        }
                        int col = nt * 16 + (lane & 15);
                        float bias = b1[col];
                        int kt2 = col >> 5, q2 = (col >> 3) & 3, e2 = col & 7;
                        #pragma unroll
                        for (int i2 = 0; i2 < 4; i2++) {
                            int lr = mtl * 16 + (lane >> 4) * 4 + i2;
                            float hvv = fmaxf(acc[i2] + bias, 0.f);
                            int di = ((mtl * 8 + kt2) * 64 + q2 * 16 + (lr & 15)) * 8 + e2;
                            unsigned short hi = f2bf(hvv);
                            ha[di] = hi;
                            hl[di] = f2bf(hvv - bf2f(hi));
                        }
                    }
                }
                __syncthreads();
                {   // F2: 16 tiles, 1 per wave; K=256; D += xs + b2
                    const float* b2 = W + OFF_B2 + lay * 64;
                    int mtl = w >> 2, nt = w & 3;
                    const unsigned short* pb = pkw + 98304 + lay * 16384 + nt * 4096 + lane * 8;
                    f4v acc = {0.f, 0.f, 0.f, 0.f};
                    #pragma unroll 2
                    for (int kt = 0; kt < 8; kt++) {
                        s8v ah = *(const s8v*)(ha + ((mtl * 8 + kt) * 64 + lane) * 8);
                        s8v al = *(const s8v*)(hl + ((mtl * 8 + kt) * 64 + lane) * 8);
                        s8v bh = *(const s8v*)(pb + kt * 512);
                        s8v bl = *(const s8v*)(pb + PK_ELEMS + kt * 512);
                        acc = mfma16(ah, bh, acc);
                        acc = mfma16(ah, bl, acc);
                        acc = mfma16(al, bh, acc);
                    }
                    int row0 = hh * 64 + mtl * 16 + (lane >> 4) * 4, col = nt * 16 + (lane & 15);
                    float bias = b2[col];
                    xs[row0    ][col] += acc[0] + bias;
                    xs[row0 + 1][col] += acc[1] + bias;
                    xs[row0 + 2][col] += acc[2] + bias;
                    xs[row0 + 3][col] += acc[3] + bias;
                }
                __syncthreads();
            }
        }
        ln_rm(xs, xnR, W + OFF_LNFG, W + OFF_LNFB, tid);
        __syncthreads();
    } else {
        // ================= VALU fallback path (round-1 kernel) =================
        for (int lay = 0; lay < NL; lay++) {
            ln_rm(xs, xnR, W + OFF_LN1G + lay * 64, W + OFF_LN1B + lay * 64, tid);
            __syncthreads();
            {
                #pragma unroll 1
                for (int mmat = 0; mmat < 3; mmat++) {
                    const float* wm = W + (mmat == 0 ? OFF_WQ : (mmat == 1 ? OFF_WK : OFF_WV))
                                        + lay * ND * ND;
                    unsigned short (*dstp)[72] = (mmat == 0) ? qs : ((mmat == 1) ? ks : vs);
                    float acc[8];
                    #pragma unroll
                    for (int rr = 0; rr < 8; rr++) acc[rr] = 0.f;
                    #pragma unroll 1
                    for (int ih = 0; ih < 4; ih++) {
                        float wr[16];
                        #pragma unroll
                        for (int i = 0; i < 16; i++) wr[i] = wm[(ih * 16 + i) * ND + lane];
                        #pragma unroll
                        for (int rr = 0; rr < 8; rr++)
                            fma16(&xnR[w * 8 + rr][ih * 16], wr, acc[rr]);
                    }
                    #pragma unroll
                    for (int rr = 0; rr < 8; rr++)
                        dstp[w * 8 + rr][lane] = f2bf(acc[rr]);
                }
            }
            __syncthreads();
            {
                const int head = w & 7, hh = w >> 3;
                const int h8 = head * 8;
                const int r  = lane + hh * 64;
                const float scale = 0.35355339059327373f;
                float qv[8];
                uint4 qq = *(const uint4*)&qs[r][h8];
                unpack8(qq, qv);
                #pragma unroll
                for (int d = 0; d < 8; d++) qv[d] *= scale;
                float m = -1e30f, lsum = 0.f;
                float o[8] = {0, 0, 0, 0, 0, 0, 0, 0};
                for (int base = 0; base <= r; base += 8) {
                    float sc[8];
                    #pragma unroll
                    for (int t = 0; t < 8; t++) {
                        int kk = base + t; kk = kk > 127 ? 127 : kk;
                        uint4 kr = *(const uint4*)&ks[kk][h8];
                        float kf[8]; unpack8(kr, kf);
                        float s = 0.f;
                        #pragma unroll
                        for (int d = 0; d < 8; d++) s = fmaf(qv[d], kf[d], s);
                        sc[t] = (base + t <= r) ? s : -1e30f;
                    }
                    float cm = fmaxf(fmaxf(fmaxf(sc[0], sc[1]), fmaxf(sc[2], sc[3])),
                                     fmaxf(fmaxf(sc[4], sc[5]), fmaxf(sc[6], sc[7])));
                    float nm  = fmaxf(m, cm);
                    float fac = __expf(m - nm);
                    lsum *= fac;
                    #pragma unroll
                    for (int d = 0; d < 8; d++) o[d] *= fac;
                    #pragma unroll
                    for (int t = 0; t < 8; t++) {
                        float p = __expf(sc[t] - nm);
                        int kk = base + t; kk = kk > 127 ? 127 : kk;
                        uint4 vr = *(const uint4*)&vs[kk][h8];
                        float vf[8]; unpack8(vr, vf);
                        lsum += p;
                        #pragma unroll
                        for (int d = 0; d < 8; d++) o[d] = fmaf(p, vf[d], o[d]);
                    }
                    m = nm;
                }
                float inv = 1.f / lsum;
                #pragma unroll
                for (int d = 0; d < 8; d++) xnR[r][h8 + d] = o[d] * inv;
            }
            __syncthreads();
            {
                const float* wo = W + OFF_WO + lay * ND * ND;
                float acc[8];
                #pragma unroll
                for (int rr = 0; rr < 8; rr++) acc[rr] = W[OFF_BO + lay * ND + lane];
                #pragma unroll 1
                for (int ih = 0; ih < 4; ih++) {
                    float wr[16];
                    #pragma unroll
                    for (int i = 0; i < 16; i++) wr[i] = wo[(ih * 16 + i) * ND + lane];
                    #pragma unroll
                    for (int rr = 0; rr < 8; rr++)
                        fma16(&xnR[w * 8 + rr][ih * 16], wr, acc[rr]);
                }
                #pragma unroll
                for (int rr = 0; rr < 8; rr++)
                    xs[w * 8 + rr][lane] += acc[rr];
            }
            __syncthreads();
            ln_rm(xs, xnR, W + OFF_LN2G + lay * 64, W + OFF_LN2B + lay * 64, tid);
            __syncthreads();
            {
                const float* w1 = W + OFF_W1 + lay * ND * NDF;
                const float* w2 = W + OFF_W2 + lay * NDF * ND;
                const float* b1 = W + OFF_B1 + lay * NDF;
                const float* b2 = W + OFF_B2 + lay * ND;
                for (int ch = 0; ch < 4; ch++) {
                    int rbase = ch * 32;
                    {
                        int lr = tid >> 5;
                        int j0 = (tid & 31) * 8;
                        int r  = rbase + lr;
                        float4 ba  = *(const float4*)(b1 + j0);
                        float4 bb4 = *(const float4*)(b1 + j0 + 4);
                        float a0 = ba.x,  a1 = ba.y,  a2 = ba.z,  a3 = ba.w;
                        float a4 = bb4.x, a5 = bb4.y, a6 = bb4.z, a7 = bb4.w;
                        #pragma unroll 4
                        for (int i4 = 0; i4 < ND; i4 += 4) {
                            float4 xv = *(const float4*)&xnR[r][i4];
                            #pragma unroll
                            for (int s = 0; s < 4; s++) {
                                float xvs = (s == 0) ? xv.x : (s == 1) ? xv.y
                                          : (s == 2) ? xv.z : xv.w;
                                float4 wa = *(const float4*)(w1 + (i4 + s) * NDF + j0);
                                float4 wb = *(const float4*)(w1 + (i4 + s) * NDF + j0 + 4);
                                a0 = fmaf(xvs, wa.x, a0); a1 = fmaf(xvs, wa.y, a1);
                                a2 = fmaf(xvs, wa.z, a2); a3 = fmaf(xvs, wa.w, a3);
                                a4 = fmaf(xvs, wb.x, a4); a5 = fmaf(xvs, wb.y, a5);
                                a6 = fmaf(xvs, wb.z, a6); a7 = fmaf(xvs, wb.w, a7);
                            }
                        }
                        float4 h0, h1;
                        h0.x = fmaxf(a0, 0.f); h0.y = fmaxf(a1, 0.f);
                        h0.z = fmaxf(a2, 0.f); h0.w = fmaxf(a3, 0.f);
                        h1.x = fmaxf(a4, 0.f); h1.y = fmaxf(a5, 0.f);
                        h1.z = fmaxf(a6, 0.f); h1.w = fmaxf(a7, 0.f);
                        *(float4*)&hch[lr][j0]     = h0;
                        *(float4*)&hch[lr][j0 + 4] = h1;
                    }
                    __syncthreads();
                    {
                        int lr = tid >> 5;
                        int i0 = (tid & 31) * 2;
                        int r  = rbase + lr;
                        float a0 = 0.f, a1 = 0.f;
                        #pragma unroll 4
                        for (int j4 = 0; j4 < NDF; j4 += 4) {
                            float4 hv = *(const float4*)&hch[lr][j4];
                            #pragma unroll
                            for (int s = 0; s < 4; s++) {
                                float hvs = (s == 0) ? hv.x : (s == 1) ? hv.y
                                          : (s == 2) ? hv.z : hv.w;
                                float2 w2v = *(const float2*)(w2 + (j4 + s) * ND + i0);
                                a0 = fmaf(hvs, w2v.x, a0); a1 = fmaf(hvs, w2v.y, a1);
                            }
                        }
                        float2 bb2 = *(const float2*)(b2 + i0);
                        xs[r][i0]     += a0 + bb2.x;
                        xs[r][i0 + 1] += a1 + bb2.y;
                    }
                    __syncthreads();
                }
            }
        }
        ln_rm(xs, xnR, W + OFF_LNFG, W + OFF_LNFB, tid);
        __syncthreads();
    }

    // ---- common: logits (fp32 VALU) + loss; wave owns 8 rows ----
    {
        const float* lmw = W + OFF_LMW;
        float wacc = 0.f;
        for (int rr = 0; rr < 8; rr++) {
            int r = w * 8 + rr;
            float lg  = W[OFF_LMB + lane];
            float lg2 = W[OFF_LMB + 64];
            #pragma unroll 8
            for (int i = 0; i < ND; i++) {
                float xv = xnR[r][i];
                lg  = fmaf(xv, lmw[i * NV + lane], lg);
                lg2 = fmaf(xv, lmw[i * NV + 64],  lg2);
            }
            float M = lg;
            #pragma unroll
            for (int off = 32; off; off >>= 1) M = fmaxf(M, __shfl_xor(M, off));
            M = fmaxf(M, lg2);
            float ssum = __expf(lg - M);
            #pragma unroll
            for (int off = 32; off; off >>= 1) ssum += __shfl_xor(ssum, off);
            ssum += __expf(lg2 - M);
            float lse = M + logf(ssum);
            int row = b * NT + r;
            int tg  = i64 ? (int)tgt64[row] : tgt32[row];
            float lt = (tg < 64) ? __shfl(lg, tg) : lg2;
            wacc += lt - lse;
            out[row * NV + lane] = lg;
            if (lane == 0) out[row * NV + 64] = lg2;
        }
        if (lane == 0) wsum[w] = wacc;
        __syncthreads();
        if (tid == 0) {
            float t = 0.f;
            #pragma unroll
            for (int wv = 0; wv < 16; wv++) t += wsum[wv];
            atomicAdd(loss_acc, t);
        }
    }
    __syncthreads();

    // ---- self-check: block 0 thread 0 recomputes row 0 logits (attn = v0) ----
    if (b == 0 && tid == 0) {
        float x0[ND], xn0[ND], v0[ND], h0[NDF];
        int tok0 = i64 ? (int)idx64[0] : idx32[0];
        for (int c = 0; c < ND; c++)
            x0[c] = W[OFF_TOK + tok0 * ND + c] + W[OFF_POS + c];
        for (int l = 0; l < NL; l++) {
            ln_scalar(x0, xn0, W + OFF_LN1G + l * ND, W + OFF_LN1B + l * ND);
            for (int c = 0; c < ND; c++) {
                float a = 0.f;
                for (int i = 0; i < ND; i++)
                    a += xn0[i] * W[OFF_WV + l * ND * ND + i * ND + c];
                v0[c] = a;
            }
            for (int c = 0; c < ND; c++) {
                float a = W[OFF_BO + l * ND + c];
                for (int i = 0; i < ND; i++)
                    a += v0[i] * W[OFF_WO + l * ND * ND + i * ND + c];
                x0[c] += a;
            }
            ln_scalar(x0, xn0, W + OFF_LN2G + l * ND, W + OFF_LN2B + l * ND);
            for (int j = 0; j < NDF; j++) {
                float a = W[OFF_B1 + l * NDF + j];
                for (int i = 0; i < ND; i++)
                    a += xn0[i] * W[OFF_W1 + l * ND * NDF + i * NDF + j];
                h0[j] = fmaxf(a, 0.f);
            }
            for (int c = 0; c < ND; c++) {
                float a = W[OFF_B2 + l * ND + c];
                for (int j = 0; j < NDF; j++)
                    a += h0[j] * W[OFF_W2 + l * NDF * ND + j * ND + c];
                x0[c] += a;
            }
        }
        ln_scalar(x0, xn0, W + OFF_LNFG, W + OFF_LNFB);
        bool bad = false;
        for (int v = 0; v < NV; v++) {
            float lg = W[OFF_LMB + v];
            for (int i = 0; i < ND; i++)
                lg += xn0[i] * W[OFF_LMW + i * NV + v];
            if (!(fabsf(out[v] - lg) <= 0.05f)) bad = true;   // catches NaN
        }
        if (bad) out[0] = 100.0f;
    }
}

__global__ void finalize_loss(const float* __restrict__ acc,
                              float* __restrict__ out) {
    out[NBT * NV] = -acc[0] * (1.f / (float)NBT);
}

extern "C" void kernel_launch(void* const* d_in, const int* in_sizes, int n_in,
                              void* d_out, int out_size, void* d_ws, size_t ws_size,
                              hipStream_t stream)
{
    static const int want[21] = {4160, 8192, 192, 192, 12288, 12288, 12288,
                                 12288, 192, 192, 192, 49152, 768, 49152, 192,
                                 64, 64, 4160, 65, 524288, 524288};
    int diag = 0;
    if (n_in != 21) diag = 3;
    else for (int i = 0; i < 21; i++) if (in_sizes[i] != want[i]) { diag = 3; break; }
    if (!diag && out_size != NBT * NV + 1) diag = 4;
    if (!diag && ws_size < (size_t)(OFF_FLAG + 1) * 4) diag = 5;
    if (diag) {
        diag_fill<<<(out_size + 255) / 256, 256, 0, stream>>>(
            (float*)d_out, out_size, (float)diag);
        return;
    }

    float* W = (float*)d_ws;
    float* loss_acc = W + OFF_LOSS;
    int*   flags    = (int*)(W + OFF_FLAG);
    hipMemsetAsync(W + OFF_LOSS, 0, 2 * sizeof(float), stream);

    detect_float<<<1, 256, 0, stream>>>((const unsigned short*)d_in[0], flags);
    detect_int  <<<1, 256, 0, stream>>>((const int*)d_in[19], flags);
    mfma_probe  <<<1, 64,  0, stream>>>(flags);

    CvtArgs a;
    for (int i = 0; i < 19; i++) a.p[i] = d_in[i];
    cvt_params<<<(CVT_TOTAL + 255) / 256, 256, 0, stream>>>(a, W, flags);

    int usepk = (ws_size >= NEED_WS) ? 1 : 0;
    unsigned short* pkw = (unsigned short*)(W + PKF);
    if (usepk)
        pack_weights<<<(PK_ELEMS + 255) / 256, 256, 0, stream>>>(W, pkw);

    gpt_fwd<<<NB, 1024, 0, stream>>>(W, pkw, usepk, d_in[19], d_in[20],
                                     (float*)d_out, loss_acc, flags);
    finalize_loss<<<1, 1, 0, stream>>>(loss_acc, (float*)d_out);
}

// Round 3
// 2465.534 us; speedup vs baseline: 6.0336x; 1.1261x over previous
//
#include <hip/hip_runtime.h>
#include <hip/hip_bf16.h>

#define NB  4096
#define NT  128
#define ND  64
#define NV  65
#define NL  3
#define NH  8
#define NDF 256
#define NBT (NB*NT)

// fp32 param offsets inside d_ws (element counts)
#define OFF_TOK   0
#define OFF_POS   4160
#define OFF_LN1G  12352
#define OFF_LN1B  12544
#define OFF_WQ    12736
#define OFF_WK    25024
#define OFF_WV    37312
#define OFF_WO    49600
#define OFF_BO    61888
#define OFF_LN2G  62080
#define OFF_LN2B  62272
#define OFF_W1    62464
#define OFF_B1    111616
#define OFF_W2    112384
#define OFF_B2    161536
#define OFF_LNFG  161728
#define OFF_LNFB  161792
#define OFF_LMW   161856
#define OFF_LMB   166016
#define CVT_TOTAL 166081
#define OFF_LOSS  166144   // fp32 loss accumulator slot
#define OFF_FLAG  166145   // flags: bit0 fp32 floats; bit2 int32 ints; bit3 MFMA-layout-BAD

// packed bf16 weights (hi + lo) appended after flag, 16B aligned
#define PKF       166148            // float offset of packed region
#define PK_ELEMS  147456            // bf16 elements per copy (hi), lo mirrors at +PK_ELEMS
#define NEED_WS   ((size_t)(PKF + PK_ELEMS) * 4)   // lo+hi = PK_ELEMS floats total

typedef short s8v  __attribute__((ext_vector_type(8)));
typedef float f4v  __attribute__((ext_vector_type(4)));

struct CvtArgs { const void* p[19]; };

__device__ __forceinline__ unsigned short f2bf(float x) {
    unsigned int u = __float_as_uint(x);
    u = (u + 0x7fffu + ((u >> 16) & 1u)) >> 16;   // RNE
    return (unsigned short)u;
}
__device__ __forceinline__ float bf2f(unsigned short h) {
    return __uint_as_float(((unsigned int)h) << 16);
}
__device__ __forceinline__ f4v mfma16(s8v a, s8v b, f4v c) {
    return __builtin_amdgcn_mfma_f32_16x16x32_bf16(a, b, c, 0, 0, 0);
}

__global__ void diag_fill(float* __restrict__ out, int n, float val) {
    int i = blockIdx.x * 256 + threadIdx.x;
    if (i < n) out[i] = val;
}

__global__ void detect_float(const unsigned short* __restrict__ tok,
                             int* __restrict__ flags) {
    int bad = 0;
    for (int i = threadIdx.x; i < 4096; i += 256) {
        float v = __uint_as_float(((unsigned int)tok[i]) << 16);
        if (!(fabsf(v) < 1000.f)) bad = 1;
    }
    if (bad) atomicOr(flags, 1);
}

__global__ void detect_int(const int* __restrict__ idx32,
                           int* __restrict__ flags) {
    int proven = 0;
    #pragma unroll
    for (int j = 0; j < 8; j++) {
        int slot = 2 * (threadIdx.x * 8 + j) + 1;
        if (idx32[slot] != 0) proven = 1;
    }
    if (proven) atomicOr(flags, 4);
}

// param conversion (bf16 or fp32 -> fp32) into workspace
__global__ void cvt_params(CvtArgs a, float* __restrict__ W,
                           const int* __restrict__ flags) {
    int tid = blockIdx.x * 256 + threadIdx.x;
    if (tid >= CVT_TOTAL) return;
    const int offs[20] = {0,4160,12352,12544,12736,25024,37312,49600,61888,
                          62080,62272,62464,111616,112384,161536,161728,
                          161792,161856,166016,166081};
    int s = 0;
    #pragma unroll
    for (int k = 1; k < 19; k++) s += (tid >= offs[k]);
    int local = tid - offs[s];
    if (*flags & 1) {
        W[tid] = ((const float*)a.p[s])[local];
    } else {
        unsigned int v = ((const unsigned short*)a.p[s])[local];
        W[tid] = __uint_as_float(v << 16);
    }
}

// Pack matmul weights into MFMA b-frag order, hi+lo bf16.
// Fragment model (B operand of mfma_f32_16x16x32_bf16):
//   lane l, elem e holds B[kt*32 + (l>>4)*8 + e][nt*16 + (l&15)]
// Tile order t = nt*KT + kt; element p enumerates [group][layer][t][l][e].
__global__ void pack_weights(const float* __restrict__ W,
                             unsigned short* __restrict__ pkw) {
    int p = blockIdx.x * 256 + threadIdx.x;
    if (p >= PK_ELEMS) return;
    int srcoff, K, N, perlay, local, ktbits;
    if (p < 49152) {
        int grp = p / 12288; local = p % 12288;
        srcoff = (grp == 0) ? OFF_WQ : (grp == 1) ? OFF_WK
               : (grp == 2) ? OFF_WV : OFF_WO;
        K = 64; N = 64; perlay = 4096; ktbits = 1;
    } else if (p < 98304) {
        local = p - 49152; srcoff = OFF_W1; K = 64; N = 256;
        perlay = 16384; ktbits = 1;
    } else {
        local = p - 98304; srcoff = OFF_W2; K = 256; N = 64;
        perlay = 16384; ktbits = 3;
    }
    int lay = local / perlay, rem = local % perlay;
    int t = rem >> 9, le = rem & 511, l = le >> 3, e = le & 7;
    int kt = t & ((1 << ktbits) - 1), nt = t >> ktbits;
    int row = kt * 32 + (l >> 4) * 8 + e;
    int col = nt * 16 + (l & 15);
    float v = W[srcoff + lay * K * N + row * N + col];
    unsigned short hi = f2bf(v);
    pkw[p] = hi;
    pkw[PK_ELEMS + p] = f2bf(v - bf2f(hi));
}

// Verify assumed A/B operand layout against the HW-verified C/D layout using
// asymmetric exact-integer matrices. On mismatch set flags bit3 -> VALU path.
__global__ void mfma_probe(int* __restrict__ flags) {
    int l = threadIdx.x;
    s8v av, bv;
    int i = l & 15;
    #pragma unroll
    for (int e = 0; e < 8; e++) {
        int k = (l >> 4) * 8 + e;
        av[e] = (short)f2bf((float)(((i * 5 + k * 3) & 7) - 3));
        bv[e] = (short)f2bf((float)(((k * 7 + i * 11) & 7) - 4));
    }
    f4v c = {0.f, 0.f, 0.f, 0.f};
    c = mfma16(av, bv, c);
    int bad = 0;
    #pragma unroll
    for (int reg = 0; reg < 4; reg++) {
        int row = (l >> 4) * 4 + reg, col = l & 15;
        float exp = 0.f;
        for (int k = 0; k < 32; k++)
            exp += (float)(((row * 5 + k * 3) & 7) - 3) *
                   (float)(((k * 7 + col * 11) & 7) - 4);
        if (c[reg] != exp) bad = 1;
    }
    if (bad) atomicOr(flags, 8);
}

__device__ __forceinline__ void unpack8(uint4 u, float* f) {
    f[0] = __uint_as_float(u.x << 16); f[1] = __uint_as_float(u.x & 0xffff0000u);
    f[2] = __uint_as_float(u.y << 16); f[3] = __uint_as_float(u.y & 0xffff0000u);
    f[4] = __uint_as_float(u.z << 16); f[5] = __uint_as_float(u.z & 0xffff0000u);
    f[6] = __uint_as_float(u.w << 16); f[7] = __uint_as_float(u.w & 0xffff0000u);
}

// LayerNorm over D=64, 8 threads per row, fp32 row-major output
__device__ __forceinline__ void ln_rm(const float (*src)[68], float (*dst)[68],
                                      const float* __restrict__ g,
                                      const float* __restrict__ bb, int tid) {
    int r = tid >> 3, q = tid & 7;
    int c0 = q * 8;
    float s = 0.f, s2 = 0.f;
    #pragma unroll
    for (int c = 0; c < 8; c++) { float v = src[r][c0 + c]; s += v; s2 += v * v; }
    s += __shfl_xor(s, 1);  s2 += __shfl_xor(s2, 1);
    s += __shfl_xor(s, 2);  s2 += __shfl_xor(s2, 2);
    s += __shfl_xor(s, 4);  s2 += __shfl_xor(s2, 4);
    float mu   = s  * (1.f / 64.f);
    float var  = s2 * (1.f / 64.f) - mu * mu;
    float rstd = rsqrtf(var + 1e-5f);
    #pragma unroll
    for (int c = 0; c < 8; c++) {
        int cc = c0 + c;
        dst[r][cc] = (src[r][cc] - mu) * rstd * g[cc] + bb[cc];
    }
}

// LayerNorm writing hi/lo bf16 a-frag layout: element (r,col) at
// ((  (r>>4)*2 + (col>>5) )*64 + ((col>>3)&3)*16 + (r&15))*8 + (col&7)
__device__ __forceinline__ void ln_frag(const float (*src)[68],
        unsigned short* __restrict__ dhi, unsigned short* __restrict__ dlo,
        const float* __restrict__ g, const float* __restrict__ bb, int tid) {
    int r = tid >> 3, q = tid & 7, c0 = q * 8;
    float s = 0.f, s2 = 0.f;
    #pragma unroll
    for (int c = 0; c < 8; c++) { float v = src[r][c0 + c]; s += v; s2 += v * v; }
    s += __shfl_xor(s, 1);  s2 += __shfl_xor(s2, 1);
    s += __shfl_xor(s, 2);  s2 += __shfl_xor(s2, 2);
    s += __shfl_xor(s, 4);  s2 += __shfl_xor(s2, 4);
    float mu   = s  * (1.f / 64.f);
    float var  = s2 * (1.f / 64.f) - mu * mu;
    float rstd = rsqrtf(var + 1e-5f);
    unsigned uh[4], ul[4];
    #pragma unroll
    for (int c2 = 0; c2 < 4; c2++) {
        float y0 = (src[r][c0 + c2*2    ] - mu) * rstd * g[c0 + c2*2    ] + bb[c0 + c2*2    ];
        float y1 = (src[r][c0 + c2*2 + 1] - mu) * rstd * g[c0 + c2*2 + 1] + bb[c0 + c2*2 + 1];
        unsigned short h0 = f2bf(y0), h1 = f2bf(y1);
        uh[c2] = (unsigned)h0 | ((unsigned)h1 << 16);
        ul[c2] = (unsigned)f2bf(y0 - bf2f(h0)) | ((unsigned)f2bf(y1 - bf2f(h1)) << 16);
    }
    int di = (((r >> 4) * 2 + (q >> 2)) * 64 + (q & 3) * 16 + (r & 15)) * 8;
    *(uint4*)(dhi + di) = make_uint4(uh[0], uh[1], uh[2], uh[3]);
    *(uint4*)(dlo + di) = make_uint4(ul[0], ul[1], ul[2], ul[3]);
}

// 16 FMAs of one activation row segment against cached weights (VALU path)
__device__ __forceinline__ void fma16(const float* xr, const float* wr, float& a) {
    float4 x0 = *(const float4*)(xr);
    float4 x1 = *(const float4*)(xr + 4);
    float4 x2 = *(const float4*)(xr + 8);
    float4 x3 = *(const float4*)(xr + 12);
    a = fmaf(x0.x, wr[0],  a); a = fmaf(x0.y, wr[1],  a);
    a = fmaf(x0.z, wr[2],  a); a = fmaf(x0.w, wr[3],  a);
    a = fmaf(x1.x, wr[4],  a); a = fmaf(x1.y, wr[5],  a);
    a = fmaf(x1.z, wr[6],  a); a = fmaf(x1.w, wr[7],  a);
    a = fmaf(x2.x, wr[8],  a); a = fmaf(x2.y, wr[9],  a);
    a = fmaf(x2.z, wr[10], a); a = fmaf(x2.w, wr[11], a);
    a = fmaf(x3.x, wr[12], a); a = fmaf(x3.y, wr[13], a);
    a = fmaf(x3.z, wr[14], a); a = fmaf(x3.w, wr[15], a);
}

// scalar LN for the self-check path
__device__ void ln_scalar(const float* x, float* o,
                          const float* g, const float* bb) {
    float mu = 0.f;
    for (int i = 0; i < ND; i++) mu += x[i];
    mu *= (1.f / 64.f);
    float var = 0.f;
    for (int i = 0; i < ND; i++) { float d = x[i] - mu; var += d * d; }
    var *= (1.f / 64.f);
    float rstd = rsqrtf(var + 1e-5f);
    for (int i = 0; i < ND; i++) o[i] = (x[i] - mu) * rstd * g[i] + bb[i];
}

__global__ __launch_bounds__(1024, 4) void gpt_fwd(
    const float* __restrict__ W, const unsigned short* __restrict__ pkw,
    int usepk, const void* __restrict__ idxp, const void* __restrict__ tgtp,
    float* __restrict__ out, float* __restrict__ loss_acc,
    const int* __restrict__ flags)
{
    __shared__ alignas(16) float xs[NT][68];          // residual (34.8KB)
    __shared__ alignas(16) unsigned char regB[34816]; // xah+xal frags OR xnR fp32
    __shared__ alignas(16) unsigned char uni[65536];  // q/k/vb/pscr OR hidden OR v1
    __shared__ alignas(16) unsigned short zblk[8];    // 16B of zeros (pad frags)
    __shared__ float wsum[16];

    float (*xnR)[68] = (float (*)[68])regB;
    unsigned short* xah = (unsigned short*)regB;            // [8mt][2kt][64][8]
    unsigned short* xal = (unsigned short*)(regB + 16384);
    // MFMA-path attention buffers (inside uni):
    unsigned short* q_lds = (unsigned short*)uni;           // [8 head][128][8]
    unsigned short* k_lds = (unsigned short*)(uni + 16384); // [8 head][128][8]
    unsigned short* vb    = (unsigned short*)(uni + 32768); // [8][4kt][4g][8c][8e]
    // per-wave P scratch at uni + 49152 (16 waves x 1KB)
    // VALU-path overlays:
    unsigned short (*qs)[72] = (unsigned short (*)[72])(uni);
    unsigned short (*ks)[72] = (unsigned short (*)[72])(uni + 18432);
    unsigned short (*vs)[72] = (unsigned short (*)[72])(uni + 36864);
    unsigned short* ha = (unsigned short*)uni;              // [4mt][8kt][64][8]
    unsigned short* hl = (unsigned short*)(uni + 32768);
    float (*hch)[264] = (float (*)[264])uni;                // VALU-path hidden

    const int tid  = threadIdx.x;
    const int lane = tid & 63;
    const int w    = tid >> 6;                              // 0..15
    const int b    = blockIdx.x;
    const int fl   = *flags;
    const bool i64 = !(fl & 4);
    const bool use_mfma = usepk && !(fl & 8);
    const int*       idx32 = (const int*)idxp;
    const long long* idx64 = (const long long*)idxp;
    const int*       tgt32 = (const int*)tgtp;
    const long long* tgt64 = (const long long*)tgtp;

    if (tid < 8) zblk[tid] = 0;

    // ---- embed: x = tok_emb[idx] + pos_emb ----
    for (int e = tid * 4; e < NT * ND; e += 4096) {
        int r = e >> 6, c = e & 63;
        int n = b * NT + r;
        int tok = i64 ? (int)idx64[n] : idx32[n];
        float4 te = *(const float4*)&W[OFF_TOK + tok * ND + c];
        float4 pe = *(const float4*)&W[OFF_POS + r * ND + c];
        float4 xv;
        xv.x = te.x + pe.x; xv.y = te.y + pe.y;
        xv.z = te.z + pe.z; xv.w = te.w + pe.w;
        *(float4*)&xs[r][c] = xv;
    }
    __syncthreads();

    if (use_mfma) {
        // ================= MFMA path =================
        for (int lay = 0; lay < NL; lay++) {
            ln_frag(xs, xah, xal, W + OFF_LN1G + lay * 64, W + OFF_LN1B + lay * 64, tid);
            __syncthreads();

            // ---- QKV: 96 tiles (mat,mt,nt), 6 per wave -> q_lds/k_lds/vb ----
            {
                const unsigned short* pbase = pkw + lay * 4096;
                #pragma unroll 1
                for (int i = 0; i < 6; i++) {
                    int ft = w * 6 + i;
                    int mat = ft >> 5, mt = (ft >> 2) & 7, nt = ft & 3;
                    const unsigned short* pb = pbase + mat * 12288 + nt * 1024 + lane * 8;
                    f4v acc = {0.f, 0.f, 0.f, 0.f};
                    #pragma unroll
                    for (int kt = 0; kt < 2; kt++) {
                        s8v ah = *(const s8v*)(xah + ((mt * 2 + kt) * 64 + lane) * 8);
                        s8v al = *(const s8v*)(xal + ((mt * 2 + kt) * 64 + lane) * 8);
                        s8v bh = *(const s8v*)(pb + kt * 512);
                        s8v bl = *(const s8v*)(pb + PK_ELEMS + kt * 512);
                        acc = mfma16(ah, bh, acc);
                        acc = mfma16(ah, bl, acc);
                        acc = mfma16(al, bh, acc);
                    }
                    int row0 = mt * 16 + (lane >> 4) * 4;
                    int fullcol = nt * 16 + (lane & 15);
                    int head = fullcol >> 3, dim = fullcol & 7;
                    if (mat == 0) {
                        #pragma unroll
                        for (int i2 = 0; i2 < 4; i2++)
                            q_lds[(head * 128 + row0 + i2) * 8 + dim] =
                                f2bf(acc[i2] * 0.35355339059327373f);
                    } else if (mat == 1) {
                        #pragma unroll
                        for (int i2 = 0; i2 < 4; i2++)
                            k_lds[(head * 128 + row0 + i2) * 8 + dim] = f2bf(acc[i2]);
                    } else {
                        #pragma unroll
                        for (int i2 = 0; i2 < 4; i2++) {
                            int key = row0 + i2;
                            vb[((((head * 4) + (key >> 5)) * 4 + ((key >> 3) & 3)) * 8
                                + dim) * 8 + (key & 7)] = f2bf(acc[i2]);
                        }
                    }
                }
            }
            __syncthreads();

            // ---- attention via MFMA: wave owns 4 (head,mt) tiles ----
            {
                unsigned short* pscr = (unsigned short*)(uni + 49152) + w * 512; // [16][32]
                const int cl = lane & 15, g = lane >> 4;
                #pragma unroll 1
                for (int ti = 0; ti < 4; ti++) {
                    int t = w + ti * 16;            // 0..63
                    int mt = t >> 3, head = t & 7;
                    // Q a-frag: k<8 in lanes 0-15, zeros elsewhere
                    const unsigned short* qsrc = (lane < 16)
                        ? q_lds + (head * 128 + mt * 16 + cl) * 8 : zblk;
                    s8v qa = *(const s8v*)qsrc;
                    f4v sv[8];
                    #pragma unroll
                    for (int nt = 0; nt < 8; nt++) {
                        sv[nt] = (f4v){0.f, 0.f, 0.f, 0.f};
                        if (nt <= mt) {
                            const unsigned short* ksrc = (lane < 16)
                                ? k_lds + (head * 128 + nt * 16 + cl) * 8 : zblk;
                            s8v kb = *(const s8v*)ksrc;
                            sv[nt] = mfma16(qa, kb, sv[nt]);
                            if (nt == mt) {     // diagonal causal mask
                                #pragma unroll
                                for (int i2 = 0; i2 < 4; i2++)
                                    sv[nt][i2] = (cl <= g * 4 + i2) ? sv[nt][i2] : -1e30f;
                            }
                        }
                    }
                    // row max (rows live in 16-lane groups; cols across cl and nt)
                    float mx[4] = {-1e30f, -1e30f, -1e30f, -1e30f};
                    #pragma unroll
                    for (int nt = 0; nt < 8; nt++)
                        if (nt <= mt) {
                            #pragma unroll
                            for (int i2 = 0; i2 < 4; i2++)
                                mx[i2] = fmaxf(mx[i2], sv[nt][i2]);
                        }
                    #pragma unroll
                    for (int i2 = 0; i2 < 4; i2++) {
                        mx[i2] = fmaxf(mx[i2], __shfl_xor(mx[i2], 1));
                        mx[i2] = fmaxf(mx[i2], __shfl_xor(mx[i2], 2));
                        mx[i2] = fmaxf(mx[i2], __shfl_xor(mx[i2], 4));
                        mx[i2] = fmaxf(mx[i2], __shfl_xor(mx[i2], 8));
                    }
                    float sm[4] = {0.f, 0.f, 0.f, 0.f};
                    #pragma unroll
                    for (int nt = 0; nt < 8; nt++)
                        if (nt <= mt) {
                            #pragma unroll
                            for (int i2 = 0; i2 < 4; i2++) {
                                float p = __expf(sv[nt][i2] - mx[i2]);
                                sv[nt][i2] = p;
                                sm[i2] += p;
                            }
                        }
                    #pragma unroll
                    for (int i2 = 0; i2 < 4; i2++) {
                        sm[i2] += __shfl_xor(sm[i2], 1);
                        sm[i2] += __shfl_xor(sm[i2], 2);
                        sm[i2] += __shfl_xor(sm[i2], 4);
                        sm[i2] += __shfl_xor(sm[i2], 8);
                    }
                    float inv[4];
                    #pragma unroll
                    for (int i2 = 0; i2 < 4; i2++) inv[i2] = 1.f / sm[i2];
                    // PV: bounce P (bf16, a-frag order) through wave scratch
                    f4v o = {0.f, 0.f, 0.f, 0.f};
                    #pragma unroll
                    for (int kt = 0; kt < 4; kt++) {
                        if (kt <= (mt >> 1)) {
                            #pragma unroll
                            for (int s2 = 0; s2 < 2; s2++) {
                                int nt = kt * 2 + s2;
                                #pragma unroll
                                for (int i2 = 0; i2 < 4; i2++) {
                                    float pv = (nt <= mt) ? sv[nt][i2] * inv[i2] : 0.f;
                                    pscr[(g * 4 + i2) * 32 + s2 * 16 + cl] = f2bf(pv);
                                }
                            }
                            s8v pa = *(const s8v*)(pscr + cl * 32 + g * 8);
                            const unsigned short* vsrc = (cl < 8)
                                ? vb + ((((head * 4) + kt) * 4 + g) * 8 + cl) * 8 : zblk;
                            s8v vf = *(const s8v*)vsrc;
                            o = mfma16(pa, vf, o);
                        }
                    }
                    // write attn output as hi/lo a-frags for WO
                    if (cl < 8) {
                        #pragma unroll
                        for (int i2 = 0; i2 < 4; i2++) {
                            int r = mt * 16 + g * 4 + i2;
                            float y = o[i2];
                            unsigned short h = f2bf(y);
                            int di = (((r >> 4) * 2 + (head >> 2)) * 64
                                      + (head & 3) * 16 + (r & 15)) * 8 + cl;
                            xah[di] = h;
                            xal[di] = f2bf(y - bf2f(h));
                        }
                    }
                }
            }
            __syncthreads();

            // ---- WO: 32 tiles, 2 per wave; D += xs ----
            {
                const unsigned short* pbase = pkw + 36864 + lay * 4096;
                const float* bo = W + OFF_BO + lay * 64;
                #pragma unroll 1
                for (int i = 0; i < 2; i++) {
                    int ft = w * 2 + i;
                    int mt = ft >> 2, nt = ft & 3;
                    const unsigned short* pb = pbase + nt * 1024 + lane * 8;
                    f4v acc = {0.f, 0.f, 0.f, 0.f};
                    #pragma unroll
                    for (int kt = 0; kt < 2; kt++) {
                        s8v ah = *(const s8v*)(xah + ((mt * 2 + kt) * 64 + lane) * 8);
                        s8v al = *(const s8v*)(xal + ((mt * 2 + kt) * 64 + lane) * 8);
                        s8v bh = *(const s8v*)(pb + kt * 512);
                        s8v bl = *(const s8v*)(pb + PK_ELEMS + kt * 512);
                        acc = mfma16(ah, bh, acc);
                        acc = mfma16(ah, bl, acc);
                        acc = mfma16(al, bh, acc);
                    }
                    int row0 = mt * 16 + (lane >> 4) * 4, col = nt * 16 + (lane & 15);
                    float bias = bo[col];
                    xs[row0    ][col] += acc[0] + bias;
                    xs[row0 + 1][col] += acc[1] + bias;
                    xs[row0 + 2][col] += acc[2] + bias;
                    xs[row0 + 3][col] += acc[3] + bias;
                }
            }
            __syncthreads();

            ln_frag(xs, xah, xal, W + OFF_LN2G + lay * 64, W + OFF_LN2B + lay * 64, tid);
            __syncthreads();

            // ---- FFN in 64-row halves ----
            for (int hh = 0; hh < 2; hh++) {
                {   // F1: 64 tiles, 4 per wave; relu -> hidden frags
                    const float* b1 = W + OFF_B1 + lay * 256;
                    #pragma unroll 1
                    for (int i = 0; i < 4; i++) {
                        int ft = w * 4 + i;
                        int mtl = ft >> 4, nt = ft & 15;
                        int mt = hh * 4 + mtl;
                        const unsigned short* pb = pkw + 49152 + lay * 16384 + nt * 1024 + lane * 8;
                        f4v acc = {0.f, 0.f, 0.f, 0.f};
                        #pragma unroll
                        for (int kt = 0; kt < 2; kt++) {
                            s8v ah = *(const s8v*)(xah + ((mt * 2 + kt) * 64 + lane) * 8);
                            s8v al = *(const s8v*)(xal + ((mt * 2 + kt) * 64 + lane) * 8);
                            s8v bh = *(const s8v*)(pb + kt * 512);
                            s8v bl = *(const s8v*)(pb + PK_ELEMS + kt * 512);
                            acc = mfma16(ah, bh, acc);
                            acc = mfma16(ah, bl, acc);
                            acc = mfma16(al, bh, acc);
                        }
                        int col = nt * 16 + (lane & 15);
                        float bias = b1[col];
                        int kt2 = col >> 5, q2 = (col >> 3) & 3, e2 = col & 7;
                        #pragma unroll
                        for (int i2 = 0; i2 < 4; i2++) {
                            int lr = mtl * 16 + (lane >> 4) * 4 + i2;
                            float hvv = fmaxf(acc[i2] + bias, 0.f);
                            int di = ((mtl * 8 + kt2) * 64 + q2 * 16 + (lr & 15)) * 8 + e2;
                            unsigned short hi = f2bf(hvv);
                            ha[di] = hi;
                            hl[di] = f2bf(hvv - bf2f(hi));
                        }
                    }
                }
                __syncthreads();
                {   // F2: 16 tiles, 1 per wave; K=256; D += xs + b2
                    const float* b2 = W + OFF_B2 + lay * 64;
                    int mtl = w >> 2, nt = w & 3;
                    const unsigned short* pb = pkw + 98304 + lay * 16384 + nt * 4096 + lane * 8;
                    f4v acc = {0.f, 0.f, 0.f, 0.f};
                    #pragma unroll 2
                    for (int kt = 0; kt < 8; kt++) {
                        s8v ah = *(const s8v*)(ha + ((mtl * 8 + kt) * 64 + lane) * 8);
                        s8v al = *(const s8v*)(hl + ((mtl * 8 + kt) * 64 + lane) * 8);
                        s8v bh = *(const s8v*)(pb + kt * 512);
                        s8v bl = *(const s8v*)(pb + PK_ELEMS + kt * 512);
                        acc = mfma16(ah, bh, acc);
                        acc = mfma16(ah, bl, acc);
                        acc = mfma16(al, bh, acc);
                    }
                    int row0 = hh * 64 + mtl * 16 + (lane >> 4) * 4, col = nt * 16 + (lane & 15);
                    float bias = b2[col];
                    xs[row0    ][col] += acc[0] + bias;
                    xs[row0 + 1][col] += acc[1] + bias;
                    xs[row0 + 2][col] += acc[2] + bias;
                    xs[row0 + 3][col] += acc[3] + bias;
                }
                __syncthreads();
            }
        }
        ln_rm(xs, xnR, W + OFF_LNFG, W + OFF_LNFB, tid);
        __syncthreads();
    } else {
        // ================= VALU fallback path (round-1 kernel) =================
        for (int lay = 0; lay < NL; lay++) {
            ln_rm(xs, xnR, W + OFF_LN1G + lay * 64, W + OFF_LN1B + lay * 64, tid);
            __syncthreads();
            {
                #pragma unroll 1
                for (int mmat = 0; mmat < 3; mmat++) {
                    const float* wm = W + (mmat == 0 ? OFF_WQ : (mmat == 1 ? OFF_WK : OFF_WV))
                                        + lay * ND * ND;
                    unsigned short (*dstp)[72] = (mmat == 0) ? qs : ((mmat == 1) ? ks : vs);
                    float acc[8];
                    #pragma unroll
                    for (int rr = 0; rr < 8; rr++) acc[rr] = 0.f;
                    #pragma unroll 1
                    for (int ih = 0; ih < 4; ih++) {
                        float wr[16];
                        #pragma unroll
                        for (int i = 0; i < 16; i++) wr[i] = wm[(ih * 16 + i) * ND + lane];
                        #pragma unroll
                        for (int rr = 0; rr < 8; rr++)
                            fma16(&xnR[w * 8 + rr][ih * 16], wr, acc[rr]);
                    }
                    #pragma unroll
                    for (int rr = 0; rr < 8; rr++)
                        dstp[w * 8 + rr][lane] = f2bf(acc[rr]);
                }
            }
            __syncthreads();
            {
                const int head = w & 7, hh = w >> 3;
                const int h8 = head * 8;
                const int r  = lane + hh * 64;
                const float scale = 0.35355339059327373f;
                float qv[8];
                uint4 qq = *(const uint4*)&qs[r][h8];
                unpack8(qq, qv);
                #pragma unroll
                for (int d = 0; d < 8; d++) qv[d] *= scale;
                float m = -1e30f, lsum = 0.f;
                float o[8] = {0, 0, 0, 0, 0, 0, 0, 0};
                for (int base = 0; base <= r; base += 8) {
                    float sc[8];
                    #pragma unroll
                    for (int t = 0; t < 8; t++) {
                        int kk = base + t; kk = kk > 127 ? 127 : kk;
                        uint4 kr = *(const uint4*)&ks[kk][h8];
                        float kf[8]; unpack8(kr, kf);
                        float s = 0.f;
                        #pragma unroll
                        for (int d = 0; d < 8; d++) s = fmaf(qv[d], kf[d], s);
                        sc[t] = (base + t <= r) ? s : -1e30f;
                    }
                    float cm = fmaxf(fmaxf(fmaxf(sc[0], sc[1]), fmaxf(sc[2], sc[3])),
                                     fmaxf(fmaxf(sc[4], sc[5]), fmaxf(sc[6], sc[7])));
                    float nm  = fmaxf(m, cm);
                    float fac = __expf(m - nm);
                    lsum *= fac;
                    #pragma unroll
                    for (int d = 0; d < 8; d++) o[d] *= fac;
                    #pragma unroll
                    for (int t = 0; t < 8; t++) {
                        float p = __expf(sc[t] - nm);
                        int kk = base + t; kk = kk > 127 ? 127 : kk;
                        uint4 vr = *(const uint4*)&vs[kk][h8];
                        float vf[8]; unpack8(vr, vf);
                        lsum += p;
                        #pragma unroll
                        for (int d = 0; d < 8; d++) o[d] = fmaf(p, vf[d], o[d]);
                    }
                    m = nm;
                }
                float inv = 1.f / lsum;
                #pragma unroll
                for (int d = 0; d < 8; d++) xnR[r][h8 + d] = o[d] * inv;
            }
            __syncthreads();
            {
                const float* wo = W + OFF_WO + lay * ND * ND;
                float acc[8];
                #pragma unroll
                for (int rr = 0; rr < 8; rr++) acc[rr] = W[OFF_BO + lay * ND + lane];
                #pragma unroll 1
                for (int ih = 0; ih < 4; ih++) {
                    float wr[16];
                    #pragma unroll
                    for (int i = 0; i < 16; i++) wr[i] = wo[(ih * 16 + i) * ND + lane];
                    #pragma unroll
                    for (int rr = 0; rr < 8; rr++)
                        fma16(&xnR[w * 8 + rr][ih * 16], wr, acc[rr]);
                }
                #pragma unroll
                for (int rr = 0; rr < 8; rr++)
                    xs[w * 8 + rr][lane] += acc[rr];
            }
            __syncthreads();
            ln_rm(xs, xnR, W + OFF_LN2G + lay * 64, W + OFF_LN2B + lay * 64, tid);
            __syncthreads();
            {
                const float* w1 = W + OFF_W1 + lay * ND * NDF;
                const float* w2 = W + OFF_W2 + lay * NDF * ND;
                const float* b1 = W + OFF_B1 + lay * NDF;
                const float* b2 = W + OFF_B2 + lay * ND;
                for (int ch = 0; ch < 4; ch++) {
                    int rbase = ch * 32;
                    {
                        int lr = tid >> 5;
                        int j0 = (tid & 31) * 8;
                        int r  = rbase + lr;
                        float4 ba  = *(const float4*)(b1 + j0);
                        float4 bb4 = *(const float4*)(b1 + j0 + 4);
                        float a0 = ba.x,  a1 = ba.y,  a2 = ba.z,  a3 = ba.w;
                        float a4 = bb4.x, a5 = bb4.y, a6 = bb4.z, a7 = bb4.w;
                        #pragma unroll 4
                        for (int i4 = 0; i4 < ND; i4 += 4) {
                            float4 xv = *(const float4*)&xnR[r][i4];
                            #pragma unroll
                            for (int s = 0; s < 4; s++) {
                                float xvs = (s == 0) ? xv.x : (s == 1) ? xv.y
                                          : (s == 2) ? xv.z : xv.w;
                                float4 wa = *(const float4*)(w1 + (i4 + s) * NDF + j0);
                                float4 wb = *(const float4*)(w1 + (i4 + s) * NDF + j0 + 4);
                                a0 = fmaf(xvs, wa.x, a0); a1 = fmaf(xvs, wa.y, a1);
                                a2 = fmaf(xvs, wa.z, a2); a3 = fmaf(xvs, wa.w, a3);
                                a4 = fmaf(xvs, wb.x, a4); a5 = fmaf(xvs, wb.y, a5);
                                a6 = fmaf(xvs, wb.z, a6); a7 = fmaf(xvs, wb.w, a7);
                            }
                        }
                        float4 h0, h1;
                        h0.x = fmaxf(a0, 0.f); h0.y = fmaxf(a1, 0.f);
                        h0.z = fmaxf(a2, 0.f); h0.w = fmaxf(a3, 0.f);
                        h1.x = fmaxf(a4, 0.f); h1.y = fmaxf(a5, 0.f);
                        h1.z = fmaxf(a6, 0.f); h1.w = fmaxf(a7, 0.f);
                        *(float4*)&hch[lr][j0]     = h0;
                        *(float4*)&hch[lr][j0 + 4] = h1;
                    }
                    __syncthreads();
                    {
                        int lr = tid >> 5;
                        int i0 = (tid & 31) * 2;
                        int r  = rbase + lr;
                        float a0 = 0.f, a1 = 0.f;
                        #pragma unroll 4
                        for (int j4 = 0; j4 < NDF; j4 += 4) {
                            float4 hv = *(const float4*)&hch[lr][j4];
                            #pragma unroll
                            for (int s = 0; s < 4; s++) {
                                float hvs = (s == 0) ? hv.x : (s == 1) ? hv.y
                                          : (s == 2) ? hv.z : hv.w;
                                float2 w2v = *(const float2*)(w2 + (j4 + s) * ND + i0);
                                a0 = fmaf(hvs, w2v.x, a0); a1 = fmaf(hvs, w2v.y, a1);
                            }
                        }
                        float2 bb2 = *(const float2*)(b2 + i0);
                        xs[r][i0]     += a0 + bb2.x;
                        xs[r][i0 + 1] += a1 + bb2.y;
                    }
                    __syncthreads();
                }
            }
        }
        ln_rm(xs, xnR, W + OFF_LNFG, W + OFF_LNFB, tid);
        __syncthreads();
    }

    // ---- common: logits (fp32 VALU) + loss; wave owns 8 rows ----
    {
        const float* lmw = W + OFF_LMW;
        float wacc = 0.f;
        for (int rr = 0; rr < 8; rr++) {
            int r = w * 8 + rr;
            float lg  = W[OFF_LMB + lane];
            float lg2 = W[OFF_LMB + 64];
            #pragma unroll 8
            for (int i = 0; i < ND; i++) {
                float xv = xnR[r][i];
                lg  = fmaf(xv, lmw[i * NV + lane], lg);
                lg2 = fmaf(xv, lmw[i * NV + 64],  lg2);
            }
            float M = lg;
            #pragma unroll
            for (int off = 32; off; off >>= 1) M = fmaxf(M, __shfl_xor(M, off));
            M = fmaxf(M, lg2);
            float ssum = __expf(lg - M);
            #pragma unroll
            for (int off = 32; off; off >>= 1) ssum += __shfl_xor(ssum, off);
            ssum += __expf(lg2 - M);
            float lse = M + logf(ssum);
            int row = b * NT + r;
            int tg  = i64 ? (int)tgt64[row] : tgt32[row];
            float lt = (tg < 64) ? __shfl(lg, tg) : lg2;
            wacc += lt - lse;
            out[row * NV + lane] = lg;
            if (lane == 0) out[row * NV + 64] = lg2;
        }
        if (lane == 0) wsum[w] = wacc;
        __syncthreads();
        if (tid == 0) {
            float t = 0.f;
            #pragma unroll
            for (int wv = 0; wv < 16; wv++) t += wsum[wv];
            atomicAdd(loss_acc, t);
        }
    }
    __syncthreads();

    // ---- self-check: block 0 thread 0 recomputes row 0 logits (attn = v0) ----
    if (b == 0 && tid == 0) {
        float x0[ND], xn0[ND], v0[ND], h0[NDF];
        int tok0 = i64 ? (int)idx64[0] : idx32[0];
        for (int c = 0; c < ND; c++)
            x0[c] = W[OFF_TOK + tok0 * ND + c] + W[OFF_POS + c];
        for (int l = 0; l < NL; l++) {
            ln_scalar(x0, xn0, W + OFF_LN1G + l * ND, W + OFF_LN1B + l * ND);
            for (int c = 0; c < ND; c++) {
                float a = 0.f;
                for (int i = 0; i < ND; i++)
                    a += xn0[i] * W[OFF_WV + l * ND * ND + i * ND + c];
                v0[c] = a;
            }
            for (int c = 0; c < ND; c++) {
                float a = W[OFF_BO + l * ND + c];
                for (int i = 0; i < ND; i++)
                    a += v0[i] * W[OFF_WO + l * ND * ND + i * ND + c];
                x0[c] += a;
            }
            ln_scalar(x0, xn0, W + OFF_LN2G + l * ND, W + OFF_LN2B + l * ND);
            for (int j = 0; j < NDF; j++) {
                float a = W[OFF_B1 + l * NDF + j];
                for (int i = 0; i < ND; i++)
                    a += xn0[i] * W[OFF_W1 + l * ND * NDF + i * NDF + j];
                h0[j] = fmaxf(a, 0.f);
            }
            for (int c = 0; c < ND; c++) {
                float a = W[OFF_B2 + l * ND + c];
                for (int j = 0; j < NDF; j++)
                    a += h0[j] * W[OFF_W2 + l * NDF * ND + j * ND + c];
                x0[c] += a;
            }
        }
        ln_scalar(x0, xn0, W + OFF_LNFG, W + OFF_LNFB);
        bool bad = false;
        for (int v = 0; v < NV; v++) {
            float lg = W[OFF_LMB + v];
            for (int i = 0; i < ND; i++)
                lg += xn0[i] * W[OFF_LMW + i * NV + v];
            if (!(fabsf(out[v] - lg) <= 0.05f)) bad = true;   // catches NaN
        }
        if (bad) out[0] = 100.0f;
    }
}

__global__ void finalize_loss(const float* __restrict__ acc,
                              float* __restrict__ out) {
    out[NBT * NV] = -acc[0] * (1.f / (float)NBT);
}

extern "C" void kernel_launch(void* const* d_in, const int* in_sizes, int n_in,
                              void* d_out, int out_size, void* d_ws, size_t ws_size,
                              hipStream_t stream)
{
    static const int want[21] = {4160, 8192, 192, 192, 12288, 12288, 12288,
                                 12288, 192, 192, 192, 49152, 768, 49152, 192,
                                 64, 64, 4160, 65, 524288, 524288};
    int diag = 0;
    if (n_in != 21) diag = 3;
    else for (int i = 0; i < 21; i++) if (in_sizes[i] != want[i]) { diag = 3; break; }
    if (!diag && out_size != NBT * NV + 1) diag = 4;
    if (!diag && ws_size < (size_t)(OFF_FLAG + 1) * 4) diag = 5;
    if (diag) {
        diag_fill<<<(out_size + 255) / 256, 256, 0, stream>>>(
            (float*)d_out, out_size, (float)diag);
        return;
    }

    float* W = (float*)d_ws;
    float* loss_acc = W + OFF_LOSS;
    int*   flags    = (int*)(W + OFF_FLAG);
    hipMemsetAsync(W + OFF_LOSS, 0, 2 * sizeof(float), stream);

    detect_float<<<1, 256, 0, stream>>>((const unsigned short*)d_in[0], flags);
    detect_int  <<<1, 256, 0, stream>>>((const int*)d_in[19], flags);
    mfma_probe  <<<1, 64,  0, stream>>>(flags);

    CvtArgs a;
    for (int i = 0; i < 19; i++) a.p[i] = d_in[i];
    cvt_params<<<(CVT_TOTAL + 255) / 256, 256, 0, stream>>>(a, W, flags);

    int usepk = (ws_size >= NEED_WS) ? 1 : 0;
    unsigned short* pkw = (unsigned short*)(W + PKF);
    if (usepk)
        pack_weights<<<(PK_ELEMS + 255) / 256, 256, 0, stream>>>(W, pkw);

    gpt_fwd<<<NB, 1024, 0, stream>>>(W, pkw, usepk, d_in[19], d_in[20],
                                     (float*)d_out, loss_acc, flags);
    finalize_loss<<<1, 1, 0, stream>>>(loss_acc, (float*)d_out);
}